// Round 2
// baseline (1001.551 us; speedup 1.0000x reference)
//
#include <hip/hip_runtime.h>
#include <hip/hip_bf16.h>

#define NN 50000
#define EE 800000
#define HH 2
#define CC 64
#define CEE 32

// ---------------- K0: combined edge weights: Wc = W_e @ W_eo, bc = b_e @ W_eo + b_eo
__global__ void k_combine(const float* __restrict__ We, const float* __restrict__ be,
                          const float* __restrict__ Weo, const float* __restrict__ beo,
                          float* __restrict__ Wc, float* __restrict__ bc) {
    int t = threadIdx.x;
    int i = t >> 5, j = t & 31;           // 32 x 32
    float s = 0.f;
    #pragma unroll
    for (int k = 0; k < 64; k++) s += We[i * 64 + k] * Weo[k * 32 + j];
    Wc[i * 32 + j] = s;
    if (t < 32) {
        float b = beo[t];
        #pragma unroll
        for (int k = 0; k < 64; k++) b += be[k] * Weo[k * 32 + t];
        bc[t] = b;
    }
}

// ---------------- K1: xl = x @ W_l + b_l ; per-node logit partials ai/aj
__global__ __launch_bounds__(128) void k_node(const float* __restrict__ x,
                                              const float* __restrict__ Wl,
                                              const float* __restrict__ bl,
                                              const float* __restrict__ att,
                                              float* __restrict__ xl,
                                              float* __restrict__ ai,
                                              float* __restrict__ aj) {
    __shared__ float sW[64 * 128];   // 32KB, one K-chunk of W_l
    __shared__ float sx[32][128];    // 16KB
    int tid = threadIdx.x;
    int n0 = blockIdx.x * 32;
    for (int i = 0; i < 32; i++) {
        int n = n0 + i;
        if (n < NN) sx[i][tid] = x[(size_t)n * 128 + tid];
    }
    float bias = bl[tid];
    int h = tid >> 6, c = tid & 63;
    float atti = att[h * 160 + c];
    float attj = att[h * 160 + 64 + c];

    float acc[32];
    #pragma unroll
    for (int j = 0; j < 32; j++) acc[j] = bias;

    for (int kc = 0; kc < 128; kc += 64) {
        __syncthreads();
        for (int i = tid; i < 64 * 128; i += 128) sW[i] = Wl[kc * 128 + i];
        __syncthreads();
        for (int k2 = 0; k2 < 64; k2++) {
            float w = sW[k2 * 128 + tid];
            #pragma unroll
            for (int j = 0; j < 32; j++) acc[j] += sx[j][kc + k2] * w;
        }
    }

    for (int j = 0; j < 32; j++) {
        int n = n0 + j;
        float v = acc[j];
        float lr = v > 0.f ? v : 0.2f * v;
        float aiv = lr * atti;
        float ajv = lr * attj;
        #pragma unroll
        for (int m = 32; m; m >>= 1) {
            aiv += __shfl_xor(aiv, m);
            ajv += __shfl_xor(ajv, m);
        }
        if (n < NN) {
            xl[(size_t)n * 128 + tid] = v;
            if ((tid & 63) == 0) { ai[n * 2 + h] = aiv; aj[n * 2 + h] = ajv; }
        }
    }
}

// ---------------- K2a: degree counts over dst
__global__ void k_count(const int* __restrict__ ei, int* __restrict__ counts) {
    int e = blockIdx.x * 256 + threadIdx.x;
    if (e < EE) atomicAdd(&counts[ei[EE + e]], 1);
}

// ---------------- scan (3 kernels)
__global__ __launch_bounds__(1024) void k_scan1(const int* __restrict__ counts,
                                                int* __restrict__ offsets,
                                                int* __restrict__ bsums) {
    __shared__ int s[1024];
    int g = blockIdx.x * 1024 + threadIdx.x;
    int v = (g < NN) ? counts[g] : 0;
    s[threadIdx.x] = v;
    __syncthreads();
    for (int st = 1; st < 1024; st <<= 1) {
        int t = (threadIdx.x >= st) ? s[threadIdx.x - st] : 0;
        __syncthreads();
        s[threadIdx.x] += t;
        __syncthreads();
    }
    if (g < NN) offsets[g] = s[threadIdx.x] - v;       // block-local exclusive
    if (threadIdx.x == 1023) bsums[blockIdx.x] = s[1023];
}

__global__ void k_scan2(int* __restrict__ bsums, int nb) {
    if (threadIdx.x == 0 && blockIdx.x == 0) {
        int c = 0;
        for (int i = 0; i < nb; i++) { int t = bsums[i]; bsums[i] = c; c += t; }
    }
}

__global__ __launch_bounds__(1024) void k_scan3(int* __restrict__ offsets,
                                                const int* __restrict__ bsums) {
    int g = blockIdx.x * 1024 + threadIdx.x;
    if (g < NN) offsets[g] += bsums[blockIdx.x];
}

// ---------------- avg_log = mean(log(cnt+1))  (sum accumulated, divided later)
__global__ void k_avg(const int* __restrict__ counts, float* __restrict__ avgsum) {
    int g = blockIdx.x * 256 + threadIdx.x;
    float v = (g < NN) ? logf((float)counts[g] + 1.0f) : 0.0f;
    #pragma unroll
    for (int m = 32; m; m >>= 1) v += __shfl_xor(v, m);
    if ((threadIdx.x & 63) == 0) atomicAdd(avgsum, v);
}

// ---------------- K3: edge transform -> logits + fused edge_out
__global__ __launch_bounds__(256) void k_edge(const float* __restrict__ ea,
                                              const int* __restrict__ ei,
                                              const float* __restrict__ We,
                                              const float* __restrict__ be,
                                              const float* __restrict__ att,
                                              const float* __restrict__ Wc,
                                              const float* __restrict__ bc,
                                              const float* __restrict__ ai,
                                              const float* __restrict__ aj,
                                              float* __restrict__ logits,
                                              float* __restrict__ eout) {
    __shared__ float sWe[32 * 64];
    __shared__ float sWc[32 * 32];
    __shared__ float sbe[64], sbc[32], satt[64];
    int tid = threadIdx.x;
    for (int i = tid; i < 2048; i += 256) sWe[i] = We[i];
    for (int i = tid; i < 1024; i += 256) sWc[i] = Wc[i];
    if (tid < 64) sbe[tid] = be[tid];
    if (tid < 32) sbc[tid] = bc[tid];
    if (tid < 64) satt[tid] = att[(tid >> 5) * 160 + 128 + (tid & 31)];
    __syncthreads();
    int e = blockIdx.x * 256 + tid;
    if (e >= EE) return;

    float a[32];
    const float4* p = (const float4*)(ea + (size_t)e * 32);
    #pragma unroll
    for (int q = 0; q < 8; q++) {
        float4 f = p[q];
        a[q * 4] = f.x; a[q * 4 + 1] = f.y; a[q * 4 + 2] = f.z; a[q * 4 + 3] = f.w;
    }
    int src = ei[e], dst = ei[EE + e];
    float lg0 = ai[dst * 2 + 0] + aj[src * 2 + 0];
    float lg1 = ai[dst * 2 + 1] + aj[src * 2 + 1];

    #pragma unroll 4
    for (int m = 0; m < 64; m++) {
        float s = sbe[m];
        #pragma unroll
        for (int k = 0; k < 32; k++) s += a[k] * sWe[k * 64 + m];
        float lr = s > 0.f ? s : 0.2f * s;
        float cb = lr * satt[m];
        if (m < 32) lg0 += cb; else lg1 += cb;
    }
    logits[(size_t)e * 2 + 0] = lg0;
    logits[(size_t)e * 2 + 1] = lg1;

    float* op = eout + (size_t)e * 32;
    #pragma unroll
    for (int j0 = 0; j0 < 32; j0 += 4) {
        float o0 = sbc[j0], o1 = sbc[j0 + 1], o2 = sbc[j0 + 2], o3 = sbc[j0 + 3];
        #pragma unroll
        for (int k = 0; k < 32; k++) {
            float av = a[k];
            o0 += av * sWc[k * 32 + j0];
            o1 += av * sWc[k * 32 + j0 + 1];
            o2 += av * sWc[k * 32 + j0 + 2];
            o3 += av * sWc[k * 32 + j0 + 3];
        }
        float4 ov = make_float4(o0, o1, o2, o3);
        *(float4*)(op + j0) = ov;
    }
}

// ---------------- K2e: CSR scatter (stores src + both-head logits per slot)
__global__ void k_scatter(const int* __restrict__ ei, const int* __restrict__ offsets,
                          int* __restrict__ fill, const float* __restrict__ logits,
                          int* __restrict__ csr_src, float* __restrict__ csr_logit) {
    int e = blockIdx.x * 256 + threadIdx.x;
    if (e >= EE) return;
    int dst = ei[EE + e], src = ei[e];
    int pos = offsets[dst] + atomicAdd(&fill[dst], 1);
    csr_src[pos] = src;
    csr_logit[(size_t)pos * 2 + 0] = logits[(size_t)e * 2 + 0];
    csr_logit[(size_t)pos * 2 + 1] = logits[(size_t)e * 2 + 1];
}

// ---------------- K4: per-(node,head) softmax + PNA aggregation; one wave each
__global__ __launch_bounds__(256) void k_aggr(const int* __restrict__ counts,
                                              const int* __restrict__ offsets,
                                              const int* __restrict__ csr_src,
                                              const float* __restrict__ csr_logit,
                                              const float* __restrict__ xl,
                                              float* __restrict__ out_ws) {
    int lane = threadIdx.x & 63;
    int wv = threadIdx.x >> 6;
    int task = blockIdx.x * 4 + wv;
    if (task >= NN * 2) return;
    int n = task >> 1, h = task & 1;
    int deg = counts[n], start = offsets[n];

    float sum = 0.f, sq = 0.f, mn = 1e30f, mx = -1e30f;
    if (deg > 0) {
        float m = -1e30f;
        for (int i = lane; i < deg; i += 64) m = fmaxf(m, csr_logit[(size_t)(start + i) * 2 + h]);
        #pragma unroll
        for (int s = 32; s; s >>= 1) m = fmaxf(m, __shfl_xor(m, s));
        float se = 0.f;
        for (int i = lane; i < deg; i += 64) se += __expf(csr_logit[(size_t)(start + i) * 2 + h] - m);
        #pragma unroll
        for (int s = 32; s; s >>= 1) se += __shfl_xor(se, s);
        float inv = 1.0f / (se + 1e-16f);
        const float* xb = xl + h * 64 + lane;
        for (int i = 0; i < deg; i++) {
            float l = csr_logit[(size_t)(start + i) * 2 + h];
            int s = csr_src[start + i];
            float alpha = __expf(l - m) * inv;
            float v = xb[(size_t)s * 128];
            float msg = v * alpha;
            sum += msg; sq += msg * msg;
            mn = fminf(mn, msg); mx = fmaxf(mx, msg);
        }
    } else {
        mn = 0.f; mx = 0.f;
    }
    float cc = deg > 0 ? (float)deg : 1.0f;
    float mean = sum / cc;
    float var = fmaxf(sq / cc - mean * mean, 0.0f);
    float sd = sqrtf(var + 1e-5f);
    float* ob = out_ws + (size_t)n * 512 + h * 256 + lane;
    ob[0] = mean; ob[64] = mn; ob[128] = mx; ob[192] = sd;
}

// ---------------- K5: node projection with per-node degree scalers folded in
// NOTE: out_att = out_amp * (avg_log/log_deg) == out exactly -> third weight
// block gets scaler 1.0, NOT avg_log/log_deg. (Round-1 bugfix.)
__global__ __launch_bounds__(256) void k_proj(const float* __restrict__ out_ws,
                                              const float* __restrict__ Wno,
                                              const float* __restrict__ bno,
                                              const int* __restrict__ counts,
                                              const float* __restrict__ avgsum,
                                              float* __restrict__ nout) {
    __shared__ float sW[64 * 192];   // 48KB: 64 r-rows x {W1,W2,W3} x 64 outputs
    int tid = threadIdx.x;
    int o = tid & 63, wv = tid >> 6;
    int n0 = blockIdx.x * 32 + wv * 8;
    float avg_log = *avgsum / (float)NN;

    float acc[8], s1[8];
    const float* arow[8];
    #pragma unroll
    for (int j = 0; j < 8; j++) {
        acc[j] = 0.f;
        int n = n0 + j;
        int nc = n < NN ? n : NN - 1;
        arow[j] = out_ws + (size_t)nc * 512;
        float cnt = (float)counts[nc];
        float degc = fmaxf(cnt, 1.0f);
        float ld = logf(degc + 1.0f);
        s1[j] = ld / avg_log;
    }

    for (int r0 = 0; r0 < 512; r0 += 64) {
        __syncthreads();
        for (int i = tid; i < 64 * 192; i += 256) {
            int rr = i / 192, rem = i % 192, which = rem >> 6, oc = rem & 63;
            int r = r0 + rr, hh = r >> 8, q = r & 255;
            sW[i] = Wno[(size_t)(hh * 768 + q + which * 256) * 64 + oc];
        }
        __syncthreads();
        for (int rr = 0; rr < 64; rr++) {
            float w1 = sW[rr * 192 + o];
            float w2 = sW[rr * 192 + 64 + o];
            float w3 = sW[rr * 192 + 128 + o];
            int r = r0 + rr;
            #pragma unroll
            for (int j = 0; j < 8; j++) {
                acc[j] += arow[j][r] * (w1 + s1[j] * w2 + w3);
            }
        }
    }
    #pragma unroll
    for (int j = 0; j < 8; j++) {
        int n = n0 + j;
        if (n < NN) nout[(size_t)n * 64 + o] = acc[j] + bno[o];
    }
}

extern "C" void kernel_launch(void* const* d_in, const int* in_sizes, int n_in,
                              void* d_out, int out_size, void* d_ws, size_t ws_size,
                              hipStream_t stream) {
    const float* x         = (const float*)d_in[0];
    const float* edge_attr = (const float*)d_in[1];
    const int*   ei        = (const int*)d_in[2];
    const float* W_l       = (const float*)d_in[3];
    const float* b_l       = (const float*)d_in[4];
    const float* W_e       = (const float*)d_in[5];
    const float* b_e       = (const float*)d_in[6];
    const float* att       = (const float*)d_in[7];
    const float* W_no      = (const float*)d_in[8];
    const float* b_no      = (const float*)d_in[9];
    const float* W_eo      = (const float*)d_in[10];
    const float* b_eo      = (const float*)d_in[11];

    float* nout = (float*)d_out;                    // [N, 64]
    float* eout = (float*)d_out + (size_t)NN * 64;  // [E, 32]

    char* ws = (char*)d_ws;
    size_t off = 0;
    auto take = [&](size_t bytes) -> char* {
        char* p = ws + off;
        off = (off + bytes + 255) & ~(size_t)255;
        return p;
    };
    float* xl        = (float*)take((size_t)NN * 128 * 4);
    float* ai        = (float*)take((size_t)NN * 2 * 4);
    float* aj        = (float*)take((size_t)NN * 2 * 4);
    float* logits    = (float*)take((size_t)EE * 2 * 4);
    float* csr_logit = (float*)take((size_t)EE * 2 * 4);
    int*   csr_src   = (int*)take((size_t)EE * 4);
    int*   counts    = (int*)take((size_t)NN * 4);
    int*   offsets   = (int*)take((size_t)NN * 4);
    int*   fill      = (int*)take((size_t)NN * 4);
    int*   bsums     = (int*)take(256 * 4);
    float* Wc        = (float*)take(32 * 32 * 4);
    float* bc        = (float*)take(32 * 4);
    float* avgsum    = (float*)take(4);
    float* out_ws    = (float*)take((size_t)NN * 512 * 4);

    hipMemsetAsync(counts, 0, (size_t)NN * 4, stream);
    hipMemsetAsync(fill, 0, (size_t)NN * 4, stream);
    hipMemsetAsync(avgsum, 0, 4, stream);

    k_combine<<<1, 1024, 0, stream>>>(W_e, b_e, W_eo, b_eo, Wc, bc);
    k_node<<<(NN + 31) / 32, 128, 0, stream>>>(x, W_l, b_l, att, xl, ai, aj);
    k_count<<<(EE + 255) / 256, 256, 0, stream>>>(ei, counts);
    int nb = (NN + 1023) / 1024;
    k_scan1<<<nb, 1024, 0, stream>>>(counts, offsets, bsums);
    k_scan2<<<1, 64, 0, stream>>>(bsums, nb);
    k_scan3<<<nb, 1024, 0, stream>>>(offsets, bsums);
    k_avg<<<(NN + 255) / 256, 256, 0, stream>>>(counts, avgsum);
    k_edge<<<(EE + 255) / 256, 256, 0, stream>>>(edge_attr, ei, W_e, b_e, att, Wc, bc,
                                                 ai, aj, logits, eout);
    k_scatter<<<(EE + 255) / 256, 256, 0, stream>>>(ei, offsets, fill, logits,
                                                    csr_src, csr_logit);
    k_aggr<<<(NN * 2 + 3) / 4, 256, 0, stream>>>(counts, offsets, csr_src, csr_logit,
                                                 xl, out_ws);
    k_proj<<<(NN + 31) / 32, 256, 0, stream>>>(out_ws, W_no, b_no, counts, avgsum, nout);
}

// Round 3
// 620.258 us; speedup vs baseline: 1.6147x; 1.6147x over previous
//
#include <hip/hip_runtime.h>
#include <hip/hip_bf16.h>

#define NN 50000
#define EE 800000
#define HH 2
#define CC 64
#define CEE 32

// ---------------- K0: combined edge weights: Wc = W_e @ W_eo, bc = b_e @ W_eo + b_eo
__global__ void k_combine(const float* __restrict__ We, const float* __restrict__ be,
                          const float* __restrict__ Weo, const float* __restrict__ beo,
                          float* __restrict__ Wc, float* __restrict__ bc) {
    int t = threadIdx.x;
    int i = t >> 5, j = t & 31;           // 32 x 32
    float s = 0.f;
    #pragma unroll
    for (int k = 0; k < 64; k++) s += We[i * 64 + k] * Weo[k * 32 + j];
    Wc[i * 32 + j] = s;
    if (t < 32) {
        float b = beo[t];
        #pragma unroll
        for (int k = 0; k < 64; k++) b += be[k] * Weo[k * 32 + t];
        bc[t] = b;
    }
}

// ---------------- K0b: projection weights combined: Wcomb[512][128]
// col o<64 : W1+W3 (identity + attenuate==identity scalers), col o>=64 : W2 (amplify)
__global__ void k_prepw(const float* __restrict__ Wno, float* __restrict__ Wcomb) {
    int r = blockIdx.x;        // 0..511  (= h*256 + agg*64 + c)
    int o = threadIdx.x;       // 0..127
    int h = r >> 8, q = r & 255;
    const float* base = Wno + (size_t)(h * 768 + q) * 64;
    float v;
    if (o < 64) v = base[o] + base[512 * 64 + o];
    else        v = base[256 * 64 + (o - 64)];
    Wcomb[r * 128 + o] = v;
}

// ---------------- K1: xl = x @ W_l + b_l ; per-node logit partials ai/aj
__global__ __launch_bounds__(128) void k_node(const float* __restrict__ x,
                                              const float* __restrict__ Wl,
                                              const float* __restrict__ bl,
                                              const float* __restrict__ att,
                                              float* __restrict__ xl,
                                              float* __restrict__ ai,
                                              float* __restrict__ aj) {
    __shared__ float sW[64 * 128];   // 32KB, one K-chunk of W_l
    __shared__ float sx[32][128];    // 16KB
    int tid = threadIdx.x;
    int n0 = blockIdx.x * 32;
    for (int i = 0; i < 32; i++) {
        int n = n0 + i;
        if (n < NN) sx[i][tid] = x[(size_t)n * 128 + tid];
    }
    float bias = bl[tid];
    int h = tid >> 6, c = tid & 63;
    float atti = att[h * 160 + c];
    float attj = att[h * 160 + 64 + c];

    float acc[32];
    #pragma unroll
    for (int j = 0; j < 32; j++) acc[j] = bias;

    for (int kc = 0; kc < 128; kc += 64) {
        __syncthreads();
        for (int i = tid; i < 64 * 128; i += 128) sW[i] = Wl[kc * 128 + i];
        __syncthreads();
        for (int k2 = 0; k2 < 64; k2++) {
            float w = sW[k2 * 128 + tid];
            #pragma unroll
            for (int j = 0; j < 32; j++) acc[j] += sx[j][kc + k2] * w;
        }
    }

    for (int j = 0; j < 32; j++) {
        int n = n0 + j;
        float v = acc[j];
        float lr = v > 0.f ? v : 0.2f * v;
        float aiv = lr * atti;
        float ajv = lr * attj;
        #pragma unroll
        for (int m = 32; m; m >>= 1) {
            aiv += __shfl_xor(aiv, m);
            ajv += __shfl_xor(ajv, m);
        }
        if (n < NN) {
            xl[(size_t)n * 128 + tid] = v;
            if ((tid & 63) == 0) { ai[n * 2 + h] = aiv; aj[n * 2 + h] = ajv; }
        }
    }
}

// ---------------- K2a: degree counts over dst
__global__ void k_count(const int* __restrict__ ei, int* __restrict__ counts) {
    int e = blockIdx.x * 256 + threadIdx.x;
    if (e < EE) atomicAdd(&counts[ei[EE + e]], 1);
}

// ---------------- scan (3 kernels)
__global__ __launch_bounds__(1024) void k_scan1(const int* __restrict__ counts,
                                                int* __restrict__ offsets,
                                                int* __restrict__ bsums) {
    __shared__ int s[1024];
    int g = blockIdx.x * 1024 + threadIdx.x;
    int v = (g < NN) ? counts[g] : 0;
    s[threadIdx.x] = v;
    __syncthreads();
    for (int st = 1; st < 1024; st <<= 1) {
        int t = (threadIdx.x >= st) ? s[threadIdx.x - st] : 0;
        __syncthreads();
        s[threadIdx.x] += t;
        __syncthreads();
    }
    if (g < NN) offsets[g] = s[threadIdx.x] - v;       // block-local exclusive
    if (threadIdx.x == 1023) bsums[blockIdx.x] = s[1023];
}

__global__ void k_scan2(int* __restrict__ bsums, int nb) {
    if (threadIdx.x == 0 && blockIdx.x == 0) {
        int c = 0;
        for (int i = 0; i < nb; i++) { int t = bsums[i]; bsums[i] = c; c += t; }
    }
}

__global__ __launch_bounds__(1024) void k_scan3(int* __restrict__ offsets,
                                                const int* __restrict__ bsums) {
    int g = blockIdx.x * 1024 + threadIdx.x;
    if (g < NN) offsets[g] += bsums[blockIdx.x];
}

// ---------------- avg_log = mean(log(cnt+1))  (sum accumulated, divided later)
__global__ void k_avg(const int* __restrict__ counts, float* __restrict__ avgsum) {
    int g = blockIdx.x * 256 + threadIdx.x;
    float v = (g < NN) ? logf((float)counts[g] + 1.0f) : 0.0f;
    #pragma unroll
    for (int m = 32; m; m >>= 1) v += __shfl_xor(v, m);
    if ((threadIdx.x & 63) == 0) atomicAdd(avgsum, v);
}

// ---------------- K3: edge transform -> logits (scattered to CSR) + fused edge_out
__global__ __launch_bounds__(256) void k_edge(const float* __restrict__ ea,
                                              const int* __restrict__ ei,
                                              const float* __restrict__ We,
                                              const float* __restrict__ be,
                                              const float* __restrict__ att,
                                              const float* __restrict__ Wc,
                                              const float* __restrict__ bc,
                                              const float* __restrict__ ai,
                                              const float* __restrict__ aj,
                                              const int* __restrict__ offsets,
                                              int* __restrict__ fill,
                                              int* __restrict__ csr_src,
                                              float* __restrict__ csr_logit,
                                              float* __restrict__ eout) {
    __shared__ float sWe[32 * 64];
    __shared__ float sWc[32 * 32];
    __shared__ float sbe[64], sbc[32], satt[64];
    int tid = threadIdx.x;
    for (int i = tid; i < 2048; i += 256) sWe[i] = We[i];
    for (int i = tid; i < 1024; i += 256) sWc[i] = Wc[i];
    if (tid < 64) sbe[tid] = be[tid];
    if (tid < 32) sbc[tid] = bc[tid];
    if (tid < 64) satt[tid] = att[(tid >> 5) * 160 + 128 + (tid & 31)];
    __syncthreads();
    int e = blockIdx.x * 256 + tid;
    if (e >= EE) return;

    float a[32];
    const float4* p = (const float4*)(ea + (size_t)e * 32);
    #pragma unroll
    for (int q = 0; q < 8; q++) {
        float4 f = p[q];
        a[q * 4] = f.x; a[q * 4 + 1] = f.y; a[q * 4 + 2] = f.z; a[q * 4 + 3] = f.w;
    }
    int src = ei[e], dst = ei[EE + e];
    float lg0 = ai[dst * 2 + 0] + aj[src * 2 + 0];
    float lg1 = ai[dst * 2 + 1] + aj[src * 2 + 1];

    #pragma unroll 4
    for (int m = 0; m < 64; m++) {
        float s = sbe[m];
        #pragma unroll
        for (int k = 0; k < 32; k++) s += a[k] * sWe[k * 64 + m];
        float lr = s > 0.f ? s : 0.2f * s;
        float cb = lr * satt[m];
        if (m < 32) lg0 += cb; else lg1 += cb;
    }
    // fused CSR scatter (replaces k_scatter)
    int pos = offsets[dst] + atomicAdd(&fill[dst], 1);
    csr_src[pos] = src;
    csr_logit[(size_t)pos * 2 + 0] = lg0;
    csr_logit[(size_t)pos * 2 + 1] = lg1;

    float* op = eout + (size_t)e * 32;
    #pragma unroll
    for (int j0 = 0; j0 < 32; j0 += 4) {
        float o0 = sbc[j0], o1 = sbc[j0 + 1], o2 = sbc[j0 + 2], o3 = sbc[j0 + 3];
        #pragma unroll
        for (int k = 0; k < 32; k++) {
            float av = a[k];
            o0 += av * sWc[k * 32 + j0];
            o1 += av * sWc[k * 32 + j0 + 1];
            o2 += av * sWc[k * 32 + j0 + 2];
            o3 += av * sWc[k * 32 + j0 + 3];
        }
        float4 ov = make_float4(o0, o1, o2, o3);
        *(float4*)(op + j0) = ov;
    }
}

// ---------------- K4: per-(node,head) softmax + PNA aggregation; one wave each
__global__ __launch_bounds__(256) void k_aggr(const int* __restrict__ counts,
                                              const int* __restrict__ offsets,
                                              const int* __restrict__ csr_src,
                                              const float* __restrict__ csr_logit,
                                              const float* __restrict__ xl,
                                              float* __restrict__ out_ws) {
    int lane = threadIdx.x & 63;
    int wv = threadIdx.x >> 6;
    int task = blockIdx.x * 4 + wv;
    if (task >= NN * 2) return;
    int n = task >> 1, h = task & 1;
    int deg = counts[n], start = offsets[n];

    float sum = 0.f, sq = 0.f, mn = 1e30f, mx = -1e30f;
    if (deg > 0) {
        float m = -1e30f;
        for (int i = lane; i < deg; i += 64) m = fmaxf(m, csr_logit[(size_t)(start + i) * 2 + h]);
        #pragma unroll
        for (int s = 32; s; s >>= 1) m = fmaxf(m, __shfl_xor(m, s));
        float se = 0.f;
        for (int i = lane; i < deg; i += 64) se += __expf(csr_logit[(size_t)(start + i) * 2 + h] - m);
        #pragma unroll
        for (int s = 32; s; s >>= 1) se += __shfl_xor(se, s);
        float inv = 1.0f / (se + 1e-16f);
        const float* xb = xl + h * 64 + lane;
        for (int i = 0; i < deg; i++) {
            float l = csr_logit[(size_t)(start + i) * 2 + h];
            int s = csr_src[start + i];
            float alpha = __expf(l - m) * inv;
            float v = xb[(size_t)s * 128];
            float msg = v * alpha;
            sum += msg; sq += msg * msg;
            mn = fminf(mn, msg); mx = fmaxf(mx, msg);
        }
    } else {
        mn = 0.f; mx = 0.f;
    }
    float cc = deg > 0 ? (float)deg : 1.0f;
    float mean = sum / cc;
    float var = fmaxf(sq / cc - mean * mean, 0.0f);
    float sd = sqrtf(var + 1e-5f);
    float* ob = out_ws + (size_t)n * 512 + h * 256 + lane;
    ob[0] = mean; ob[64] = mn; ob[128] = mx; ob[192] = sd;
}

// ---------------- K5: tiled fp32 GEMM  out = A[N,512] @ Wcomb[512,128],
// epilogue out[n][o] = P1[o] + s1[n]*P2[o] + b[o]   (P2 = cols 64..127)
__global__ __launch_bounds__(256) void k_proj2(const float* __restrict__ A,
                                               const float* __restrict__ Wcomb,
                                               const float* __restrict__ bno,
                                               const int* __restrict__ counts,
                                               const float* __restrict__ avgsum,
                                               float* __restrict__ nout) {
    __shared__ float sA[32][72];    // transposed A-tile, 72-pad keeps 16B align
    __shared__ float sB[32][128];
    int t = threadIdx.x;
    int n0 = blockIdx.x * 64;
    int g = t & 31;        // output group: cols 4g..4g+3
    int ng = t >> 5;       // node subgroup 0..7 (8 nodes each)

    float acc[8][4];
    #pragma unroll
    for (int j = 0; j < 8; j++)
        #pragma unroll
        for (int q = 0; q < 4; q++) acc[j][q] = 0.f;

    int ldn = t >> 2;              // 0..63
    int ldk = (t & 3) * 8;         // 0,8,16,24
    int an = n0 + ldn; if (an >= NN) an = NN - 1;
    const float* Arow = A + (size_t)an * 512;
    int bk = t >> 3;               // 0..31
    int bo = (t & 7) * 16;         // 0..112

    for (int kc = 0; kc < 512; kc += 32) {
        __syncthreads();
        float4 a0 = *(const float4*)(Arow + kc + ldk);
        float4 a1 = *(const float4*)(Arow + kc + ldk + 4);
        sA[ldk + 0][ldn] = a0.x; sA[ldk + 1][ldn] = a0.y;
        sA[ldk + 2][ldn] = a0.z; sA[ldk + 3][ldn] = a0.w;
        sA[ldk + 4][ldn] = a1.x; sA[ldk + 5][ldn] = a1.y;
        sA[ldk + 6][ldn] = a1.z; sA[ldk + 7][ldn] = a1.w;
        const float* bp = Wcomb + (size_t)(kc + bk) * 128 + bo;
        float4 b0 = *(const float4*)(bp);
        float4 b1 = *(const float4*)(bp + 4);
        float4 b2 = *(const float4*)(bp + 8);
        float4 b3 = *(const float4*)(bp + 12);
        *(float4*)&sB[bk][bo]      = b0;
        *(float4*)&sB[bk][bo + 4]  = b1;
        *(float4*)&sB[bk][bo + 8]  = b2;
        *(float4*)&sB[bk][bo + 12] = b3;
        __syncthreads();
        #pragma unroll 8
        for (int k = 0; k < 32; k++) {
            float4 b = *(const float4*)&sB[k][g * 4];
            float4 x0 = *(const float4*)&sA[k][ng * 8];
            float4 x1 = *(const float4*)&sA[k][ng * 8 + 4];
            float av[8] = {x0.x, x0.y, x0.z, x0.w, x1.x, x1.y, x1.z, x1.w};
            #pragma unroll
            for (int j = 0; j < 8; j++) {
                acc[j][0] += av[j] * b.x;
                acc[j][1] += av[j] * b.y;
                acc[j][2] += av[j] * b.z;
                acc[j][3] += av[j] * b.w;
            }
        }
    }

    float avg_log = *avgsum / (float)NN;
    float4 bv = *(const float4*)(bno + (g & 15) * 4);
    #pragma unroll
    for (int j = 0; j < 8; j++) {
        int n = n0 + ng * 8 + j;
        // P2 lives in lane (g+16): pull it over
        float p0 = __shfl_xor(acc[j][0], 16);
        float p1 = __shfl_xor(acc[j][1], 16);
        float p2 = __shfl_xor(acc[j][2], 16);
        float p3 = __shfl_xor(acc[j][3], 16);
        if (g < 16 && n < NN) {
            float cnt = (float)counts[n];
            float ld = logf(fmaxf(cnt, 1.0f) + 1.0f);
            float s1 = ld / avg_log;
            float4 o;
            o.x = acc[j][0] + s1 * p0 + bv.x;
            o.y = acc[j][1] + s1 * p1 + bv.y;
            o.z = acc[j][2] + s1 * p2 + bv.z;
            o.w = acc[j][3] + s1 * p3 + bv.w;
            *(float4*)(nout + (size_t)n * 64 + g * 4) = o;
        }
    }
}

extern "C" void kernel_launch(void* const* d_in, const int* in_sizes, int n_in,
                              void* d_out, int out_size, void* d_ws, size_t ws_size,
                              hipStream_t stream) {
    const float* x         = (const float*)d_in[0];
    const float* edge_attr = (const float*)d_in[1];
    const int*   ei        = (const int*)d_in[2];
    const float* W_l       = (const float*)d_in[3];
    const float* b_l       = (const float*)d_in[4];
    const float* W_e       = (const float*)d_in[5];
    const float* b_e       = (const float*)d_in[6];
    const float* att       = (const float*)d_in[7];
    const float* W_no      = (const float*)d_in[8];
    const float* b_no      = (const float*)d_in[9];
    const float* W_eo      = (const float*)d_in[10];
    const float* b_eo      = (const float*)d_in[11];

    float* nout = (float*)d_out;                    // [N, 64]
    float* eout = (float*)d_out + (size_t)NN * 64;  // [E, 32]

    char* ws = (char*)d_ws;
    size_t off = 0;
    auto take = [&](size_t bytes) -> char* {
        char* p = ws + off;
        off = (off + bytes + 255) & ~(size_t)255;
        return p;
    };
    float* xl        = (float*)take((size_t)NN * 128 * 4);
    float* ai        = (float*)take((size_t)NN * 2 * 4);
    float* aj        = (float*)take((size_t)NN * 2 * 4);
    float* csr_logit = (float*)take((size_t)EE * 2 * 4);
    int*   csr_src   = (int*)take((size_t)EE * 4);
    int*   counts    = (int*)take((size_t)NN * 4);
    int*   offsets   = (int*)take((size_t)NN * 4);
    int*   fill      = (int*)take((size_t)NN * 4);
    int*   bsums     = (int*)take(256 * 4);
    float* Wc        = (float*)take(32 * 32 * 4);
    float* bc        = (float*)take(32 * 4);
    float* Wcomb     = (float*)take(512 * 128 * 4);
    float* avgsum    = (float*)take(4);
    float* out_ws    = (float*)take((size_t)NN * 512 * 4);

    hipMemsetAsync(counts, 0, (size_t)NN * 4, stream);
    hipMemsetAsync(fill, 0, (size_t)NN * 4, stream);
    hipMemsetAsync(avgsum, 0, 4, stream);

    k_combine<<<1, 1024, 0, stream>>>(W_e, b_e, W_eo, b_eo, Wc, bc);
    k_prepw<<<512, 128, 0, stream>>>(W_no, Wcomb);
    k_node<<<(NN + 31) / 32, 128, 0, stream>>>(x, W_l, b_l, att, xl, ai, aj);
    k_count<<<(EE + 255) / 256, 256, 0, stream>>>(ei, counts);
    int nb = (NN + 1023) / 1024;
    k_scan1<<<nb, 1024, 0, stream>>>(counts, offsets, bsums);
    k_scan2<<<1, 64, 0, stream>>>(bsums, nb);
    k_scan3<<<nb, 1024, 0, stream>>>(offsets, bsums);
    k_avg<<<(NN + 255) / 256, 256, 0, stream>>>(counts, avgsum);
    k_edge<<<(EE + 255) / 256, 256, 0, stream>>>(edge_attr, ei, W_e, b_e, att, Wc, bc,
                                                 ai, aj, offsets, fill,
                                                 csr_src, csr_logit, eout);
    k_aggr<<<(NN * 2 + 3) / 4, 256, 0, stream>>>(counts, offsets, csr_src, csr_logit,
                                                 xl, out_ws);
    k_proj2<<<(NN + 63) / 64, 256, 0, stream>>>(out_ws, Wcomb, b_no, counts, avgsum, nout);
}

// Round 4
// 529.006 us; speedup vs baseline: 1.8933x; 1.1725x over previous
//
#include <hip/hip_runtime.h>
#include <hip/hip_bf16.h>

#define NN 50000
#define EE 800000
#define HH 2
#define CC 64
#define CEE 32

// ---------------- K0: combined edge weights: Wc = W_e @ W_eo, bc = b_e @ W_eo + b_eo
__global__ void k_combine(const float* __restrict__ We, const float* __restrict__ be,
                          const float* __restrict__ Weo, const float* __restrict__ beo,
                          float* __restrict__ Wc, float* __restrict__ bc) {
    int t = threadIdx.x;
    int i = t >> 5, j = t & 31;           // 32 x 32
    float s = 0.f;
    #pragma unroll
    for (int k = 0; k < 64; k++) s += We[i * 64 + k] * Weo[k * 32 + j];
    Wc[i * 32 + j] = s;
    if (t < 32) {
        float b = beo[t];
        #pragma unroll
        for (int k = 0; k < 64; k++) b += be[k] * Weo[k * 32 + t];
        bc[t] = b;
    }
}

// ---------------- K0b: projection weights combined: Wcomb[512][128]
// col o<64 : W1+W3 (identity + attenuate==identity scalers), col o>=64 : W2 (amplify)
__global__ void k_prepw(const float* __restrict__ Wno, float* __restrict__ Wcomb) {
    int r = blockIdx.x;        // 0..511  (= h*256 + agg*64 + c)
    int o = threadIdx.x;       // 0..127
    int h = r >> 8, q = r & 255;
    const float* base = Wno + (size_t)(h * 768 + q) * 64;
    float v;
    if (o < 64) v = base[o] + base[512 * 64 + o];
    else        v = base[256 * 64 + (o - 64)];
    Wcomb[r * 128 + o] = v;
}

// ---------------- K1: xl = x @ W_l + b_l ; per-node logit partials ai/aj
__global__ __launch_bounds__(128) void k_node(const float* __restrict__ x,
                                              const float* __restrict__ Wl,
                                              const float* __restrict__ bl,
                                              const float* __restrict__ att,
                                              float* __restrict__ xl,
                                              float* __restrict__ ai,
                                              float* __restrict__ aj) {
    __shared__ float sW[64 * 128];   // 32KB, one K-chunk of W_l
    __shared__ float sx[32][128];    // 16KB
    int tid = threadIdx.x;
    int n0 = blockIdx.x * 32;
    for (int i = 0; i < 32; i++) {
        int n = n0 + i;
        if (n < NN) sx[i][tid] = x[(size_t)n * 128 + tid];
    }
    float bias = bl[tid];
    int h = tid >> 6, c = tid & 63;
    float atti = att[h * 160 + c];
    float attj = att[h * 160 + 64 + c];

    float acc[32];
    #pragma unroll
    for (int j = 0; j < 32; j++) acc[j] = bias;

    for (int kc = 0; kc < 128; kc += 64) {
        __syncthreads();
        for (int i = tid; i < 64 * 128; i += 128) sW[i] = Wl[kc * 128 + i];
        __syncthreads();
        for (int k2 = 0; k2 < 64; k2++) {
            float w = sW[k2 * 128 + tid];
            #pragma unroll
            for (int j = 0; j < 32; j++) acc[j] += sx[j][kc + k2] * w;
        }
    }

    for (int j = 0; j < 32; j++) {
        int n = n0 + j;
        float v = acc[j];
        float lr = v > 0.f ? v : 0.2f * v;
        float aiv = lr * atti;
        float ajv = lr * attj;
        #pragma unroll
        for (int m = 32; m; m >>= 1) {
            aiv += __shfl_xor(aiv, m);
            ajv += __shfl_xor(ajv, m);
        }
        if (n < NN) {
            xl[(size_t)n * 128 + tid] = v;
            if ((tid & 63) == 0) { ai[n * 2 + h] = aiv; aj[n * 2 + h] = ajv; }
        }
    }
}

// ---------------- K2a: degree counts over dst
__global__ void k_count(const int* __restrict__ ei, int* __restrict__ counts) {
    int e = blockIdx.x * 256 + threadIdx.x;
    if (e < EE) atomicAdd(&counts[ei[EE + e]], 1);
}

// ---------------- scan (3 kernels); k_scan1 also folds in avg_log accumulation
__global__ __launch_bounds__(1024) void k_scan1(const int* __restrict__ counts,
                                                int* __restrict__ offsets,
                                                int* __restrict__ bsums,
                                                float* __restrict__ avgsum) {
    __shared__ int s[1024];
    int g = blockIdx.x * 1024 + threadIdx.x;
    int v = (g < NN) ? counts[g] : 0;
    s[threadIdx.x] = v;
    __syncthreads();
    for (int st = 1; st < 1024; st <<= 1) {
        int t = (threadIdx.x >= st) ? s[threadIdx.x - st] : 0;
        __syncthreads();
        s[threadIdx.x] += t;
        __syncthreads();
    }
    if (g < NN) offsets[g] = s[threadIdx.x] - v;       // block-local exclusive
    if (threadIdx.x == 1023) bsums[blockIdx.x] = s[1023];
    // folded avg: wave-reduce log(cnt+1)
    float lv = (g < NN) ? logf((float)v + 1.0f) : 0.0f;
    #pragma unroll
    for (int m = 32; m; m >>= 1) lv += __shfl_xor(lv, m);
    if ((threadIdx.x & 63) == 0) atomicAdd(avgsum, lv);
}

__global__ void k_scan2(int* __restrict__ bsums, int nb) {
    if (threadIdx.x == 0 && blockIdx.x == 0) {
        int c = 0;
        for (int i = 0; i < nb; i++) { int t = bsums[i]; bsums[i] = c; c += t; }
    }
}

__global__ __launch_bounds__(1024) void k_scan3(int* __restrict__ offsets,
                                                const int* __restrict__ bsums) {
    int g = blockIdx.x * 1024 + threadIdx.x;
    if (g < NN) offsets[g] += bsums[blockIdx.x];
}

// ---------------- K3: edge transform -> logits (scattered to CSR) + fused edge_out
__global__ __launch_bounds__(256) void k_edge(const float* __restrict__ ea,
                                              const int* __restrict__ ei,
                                              const float* __restrict__ We,
                                              const float* __restrict__ be,
                                              const float* __restrict__ att,
                                              const float* __restrict__ Wc,
                                              const float* __restrict__ bc,
                                              const float* __restrict__ ai,
                                              const float* __restrict__ aj,
                                              const int* __restrict__ offsets,
                                              int* __restrict__ fill,
                                              int* __restrict__ csr_src,
                                              float* __restrict__ csr_logit,
                                              float* __restrict__ eout) {
    __shared__ float sWe[32 * 64];
    __shared__ float sWc[32 * 32];
    __shared__ float sbe[64], sbc[32], satt[64];
    int tid = threadIdx.x;
    for (int i = tid; i < 2048; i += 256) sWe[i] = We[i];
    for (int i = tid; i < 1024; i += 256) sWc[i] = Wc[i];
    if (tid < 64) sbe[tid] = be[tid];
    if (tid < 32) sbc[tid] = bc[tid];
    if (tid < 64) satt[tid] = att[(tid >> 5) * 160 + 128 + (tid & 31)];
    __syncthreads();
    int e = blockIdx.x * 256 + tid;
    if (e >= EE) return;

    float a[32];
    const float4* p = (const float4*)(ea + (size_t)e * 32);
    #pragma unroll
    for (int q = 0; q < 8; q++) {
        float4 f = p[q];
        a[q * 4] = f.x; a[q * 4 + 1] = f.y; a[q * 4 + 2] = f.z; a[q * 4 + 3] = f.w;
    }
    int src = ei[e], dst = ei[EE + e];
    float lg0 = ai[dst * 2 + 0] + aj[src * 2 + 0];
    float lg1 = ai[dst * 2 + 1] + aj[src * 2 + 1];

    #pragma unroll 4
    for (int m = 0; m < 64; m++) {
        float s = sbe[m];
        #pragma unroll
        for (int k = 0; k < 32; k++) s += a[k] * sWe[k * 64 + m];
        float lr = s > 0.f ? s : 0.2f * s;
        float cb = lr * satt[m];
        if (m < 32) lg0 += cb; else lg1 += cb;
    }
    // fused CSR scatter
    int pos = offsets[dst] + atomicAdd(&fill[dst], 1);
    csr_src[pos] = src;
    *(float2*)(csr_logit + (size_t)pos * 2) = make_float2(lg0, lg1);

    float* op = eout + (size_t)e * 32;
    #pragma unroll
    for (int j0 = 0; j0 < 32; j0 += 4) {
        float o0 = sbc[j0], o1 = sbc[j0 + 1], o2 = sbc[j0 + 2], o3 = sbc[j0 + 3];
        #pragma unroll
        for (int k = 0; k < 32; k++) {
            float av = a[k];
            o0 += av * sWc[k * 32 + j0];
            o1 += av * sWc[k * 32 + j0 + 1];
            o2 += av * sWc[k * 32 + j0 + 2];
            o3 += av * sWc[k * 32 + j0 + 3];
        }
        float4 ov = make_float4(o0, o1, o2, o3);
        *(float4*)(op + j0) = ov;
    }
}

// ---------------- K4: one wave per NODE, both heads fused.
// lane holds channels (2*lane, 2*lane+1) of the 128-wide xl row.
__global__ __launch_bounds__(256) void k_aggr(const int* __restrict__ counts,
                                              const int* __restrict__ offsets,
                                              const int* __restrict__ csr_src,
                                              const float* __restrict__ csr_logit,
                                              const float* __restrict__ xl,
                                              float* __restrict__ out_ws) {
    int lane = threadIdx.x & 63;
    int wv = threadIdx.x >> 6;
    int n = blockIdx.x * 4 + wv;
    if (n >= NN) return;
    int deg = counts[n], start = offsets[n];

    float sum0 = 0.f, sum1 = 0.f, sq0 = 0.f, sq1 = 0.f;
    float mn0 = 1e30f, mn1 = 1e30f, mx0 = -1e30f, mx1 = -1e30f;

    if (deg > 0 && deg <= 64) {
        // ---- fast path: one edge per lane, softmax entirely in-register
        float2 lg = make_float2(-1e30f, -1e30f);
        int srcv = 0;
        if (lane < deg) {
            lg = *(const float2*)(csr_logit + (size_t)(start + lane) * 2);
            srcv = csr_src[start + lane];
        }
        float m0 = lg.x, m1 = lg.y;
        #pragma unroll
        for (int s = 32; s; s >>= 1) {
            m0 = fmaxf(m0, __shfl_xor(m0, s));
            m1 = fmaxf(m1, __shfl_xor(m1, s));
        }
        float e0 = (lane < deg) ? __expf(lg.x - m0) : 0.f;
        float e1 = (lane < deg) ? __expf(lg.y - m1) : 0.f;
        float s0 = e0, s1 = e1;
        #pragma unroll
        for (int s = 32; s; s >>= 1) {
            s0 += __shfl_xor(s0, s);
            s1 += __shfl_xor(s1, s);
        }
        float a0 = e0 / (s0 + 1e-16f);
        float a1 = e1 / (s1 + 1e-16f);

        for (int i = 0; i < deg; i++) {
            int sidx = __shfl(srcv, i);
            float al0 = __shfl(a0, i);
            float al1 = __shfl(a1, i);
            float alpha = (lane < 32) ? al0 : al1;
            float2 v = *(const float2*)(xl + (size_t)sidx * 128 + lane * 2);
            float g0 = v.x * alpha, g1 = v.y * alpha;
            sum0 += g0; sum1 += g1;
            sq0 += g0 * g0; sq1 += g1 * g1;
            mn0 = fminf(mn0, g0); mn1 = fminf(mn1, g1);
            mx0 = fmaxf(mx0, g0); mx1 = fmaxf(mx1, g1);
        }
    } else if (deg > 64) {
        // ---- generic path (rare)
        float m0 = -1e30f, m1 = -1e30f;
        for (int i = lane; i < deg; i += 64) {
            float2 lg = *(const float2*)(csr_logit + (size_t)(start + i) * 2);
            m0 = fmaxf(m0, lg.x); m1 = fmaxf(m1, lg.y);
        }
        #pragma unroll
        for (int s = 32; s; s >>= 1) {
            m0 = fmaxf(m0, __shfl_xor(m0, s));
            m1 = fmaxf(m1, __shfl_xor(m1, s));
        }
        float s0 = 0.f, s1 = 0.f;
        for (int i = lane; i < deg; i += 64) {
            float2 lg = *(const float2*)(csr_logit + (size_t)(start + i) * 2);
            s0 += __expf(lg.x - m0); s1 += __expf(lg.y - m1);
        }
        #pragma unroll
        for (int s = 32; s; s >>= 1) {
            s0 += __shfl_xor(s0, s);
            s1 += __shfl_xor(s1, s);
        }
        float inv0 = 1.0f / (s0 + 1e-16f), inv1 = 1.0f / (s1 + 1e-16f);
        for (int i = 0; i < deg; i++) {
            float2 lg = *(const float2*)(csr_logit + (size_t)(start + i) * 2);
            int sidx = csr_src[start + i];
            float al0 = __expf(lg.x - m0) * inv0;
            float al1 = __expf(lg.y - m1) * inv1;
            float alpha = (lane < 32) ? al0 : al1;
            float2 v = *(const float2*)(xl + (size_t)sidx * 128 + lane * 2);
            float g0 = v.x * alpha, g1 = v.y * alpha;
            sum0 += g0; sum1 += g1;
            sq0 += g0 * g0; sq1 += g1 * g1;
            mn0 = fminf(mn0, g0); mn1 = fminf(mn1, g1);
            mx0 = fmaxf(mx0, g0); mx1 = fmaxf(mx1, g1);
        }
    } else {
        mn0 = mn1 = mx0 = mx1 = 0.f;
    }

    float cc = deg > 0 ? (float)deg : 1.0f;
    float mean0 = sum0 / cc, mean1 = sum1 / cc;
    float sd0 = sqrtf(fmaxf(sq0 / cc - mean0 * mean0, 0.0f) + 1e-5f);
    float sd1 = sqrtf(fmaxf(sq1 / cc - mean1 * mean1, 0.0f) + 1e-5f);

    int c2 = lane * 2, h = c2 >> 6, c = c2 & 63;
    float* ob = out_ws + (size_t)n * 512 + h * 256 + c;
    *(float2*)(ob + 0)   = make_float2(mean0, mean1);
    *(float2*)(ob + 64)  = make_float2(mn0, mn1);
    *(float2*)(ob + 128) = make_float2(mx0, mx1);
    *(float2*)(ob + 192) = make_float2(sd0, sd1);
}

// ---------------- K5: tiled fp32 GEMM  out = A[N,512] @ Wcomb[512,128],
// epilogue out[n][o] = P1[o] + s1[n]*P2[o] + b[o]   (P2 = cols 64..127)
__global__ __launch_bounds__(256) void k_proj2(const float* __restrict__ A,
                                               const float* __restrict__ Wcomb,
                                               const float* __restrict__ bno,
                                               const int* __restrict__ counts,
                                               const float* __restrict__ avgsum,
                                               float* __restrict__ nout) {
    __shared__ float sA[32][72];    // transposed A-tile, 72-pad keeps 16B align
    __shared__ float sB[32][128];
    int t = threadIdx.x;
    int n0 = blockIdx.x * 64;
    int g = t & 31;        // output group: cols 4g..4g+3
    int ng = t >> 5;       // node subgroup 0..7 (8 nodes each)

    float acc[8][4];
    #pragma unroll
    for (int j = 0; j < 8; j++)
        #pragma unroll
        for (int q = 0; q < 4; q++) acc[j][q] = 0.f;

    int ldn = t >> 2;              // 0..63
    int ldk = (t & 3) * 8;         // 0,8,16,24
    int an = n0 + ldn; if (an >= NN) an = NN - 1;
    const float* Arow = A + (size_t)an * 512;
    int bk = t >> 3;               // 0..31
    int bo = (t & 7) * 16;         // 0..112

    for (int kc = 0; kc < 512; kc += 32) {
        __syncthreads();
        float4 a0 = *(const float4*)(Arow + kc + ldk);
        float4 a1 = *(const float4*)(Arow + kc + ldk + 4);
        sA[ldk + 0][ldn] = a0.x; sA[ldk + 1][ldn] = a0.y;
        sA[ldk + 2][ldn] = a0.z; sA[ldk + 3][ldn] = a0.w;
        sA[ldk + 4][ldn] = a1.x; sA[ldk + 5][ldn] = a1.y;
        sA[ldk + 6][ldn] = a1.z; sA[ldk + 7][ldn] = a1.w;
        const float* bp = Wcomb + (size_t)(kc + bk) * 128 + bo;
        float4 b0 = *(const float4*)(bp);
        float4 b1 = *(const float4*)(bp + 4);
        float4 b2 = *(const float4*)(bp + 8);
        float4 b3 = *(const float4*)(bp + 12);
        *(float4*)&sB[bk][bo]      = b0;
        *(float4*)&sB[bk][bo + 4]  = b1;
        *(float4*)&sB[bk][bo + 8]  = b2;
        *(float4*)&sB[bk][bo + 12] = b3;
        __syncthreads();
        #pragma unroll 8
        for (int k = 0; k < 32; k++) {
            float4 b = *(const float4*)&sB[k][g * 4];
            float4 x0 = *(const float4*)&sA[k][ng * 8];
            float4 x1 = *(const float4*)&sA[k][ng * 8 + 4];
            float av[8] = {x0.x, x0.y, x0.z, x0.w, x1.x, x1.y, x1.z, x1.w};
            #pragma unroll
            for (int j = 0; j < 8; j++) {
                acc[j][0] += av[j] * b.x;
                acc[j][1] += av[j] * b.y;
                acc[j][2] += av[j] * b.z;
                acc[j][3] += av[j] * b.w;
            }
        }
    }

    float avg_log = *avgsum / (float)NN;
    float4 bv = *(const float4*)(bno + (g & 15) * 4);
    #pragma unroll
    for (int j = 0; j < 8; j++) {
        int n = n0 + ng * 8 + j;
        // P2 lives in lane (g+16): pull it over
        float p0 = __shfl_xor(acc[j][0], 16);
        float p1 = __shfl_xor(acc[j][1], 16);
        float p2 = __shfl_xor(acc[j][2], 16);
        float p3 = __shfl_xor(acc[j][3], 16);
        if (g < 16 && n < NN) {
            float cnt = (float)counts[n];
            float ld = logf(fmaxf(cnt, 1.0f) + 1.0f);
            float s1 = ld / avg_log;
            float4 o;
            o.x = acc[j][0] + s1 * p0 + bv.x;
            o.y = acc[j][1] + s1 * p1 + bv.y;
            o.z = acc[j][2] + s1 * p2 + bv.z;
            o.w = acc[j][3] + s1 * p3 + bv.w;
            *(float4*)(nout + (size_t)n * 64 + g * 4) = o;
        }
    }
}

extern "C" void kernel_launch(void* const* d_in, const int* in_sizes, int n_in,
                              void* d_out, int out_size, void* d_ws, size_t ws_size,
                              hipStream_t stream) {
    const float* x         = (const float*)d_in[0];
    const float* edge_attr = (const float*)d_in[1];
    const int*   ei        = (const int*)d_in[2];
    const float* W_l       = (const float*)d_in[3];
    const float* b_l       = (const float*)d_in[4];
    const float* W_e       = (const float*)d_in[5];
    const float* b_e       = (const float*)d_in[6];
    const float* att       = (const float*)d_in[7];
    const float* W_no      = (const float*)d_in[8];
    const float* b_no      = (const float*)d_in[9];
    const float* W_eo      = (const float*)d_in[10];
    const float* b_eo      = (const float*)d_in[11];

    float* nout = (float*)d_out;                    // [N, 64]
    float* eout = (float*)d_out + (size_t)NN * 64;  // [E, 32]

    char* ws = (char*)d_ws;
    size_t off = 0;
    auto take = [&](size_t bytes) -> char* {
        char* p = ws + off;
        off = (off + bytes + 255) & ~(size_t)255;
        return p;
    };
    float* xl        = (float*)take((size_t)NN * 128 * 4);
    float* ai        = (float*)take((size_t)NN * 2 * 4);
    float* aj        = (float*)take((size_t)NN * 2 * 4);
    float* csr_logit = (float*)take((size_t)EE * 2 * 4);
    int*   csr_src   = (int*)take((size_t)EE * 4);
    int*   counts    = (int*)take((size_t)NN * 4);
    int*   offsets   = (int*)take((size_t)NN * 4);
    int*   fill      = (int*)take((size_t)NN * 4);
    int*   bsums     = (int*)take(256 * 4);
    float* Wc        = (float*)take(32 * 32 * 4);
    float* bc        = (float*)take(32 * 4);
    float* Wcomb     = (float*)take(512 * 128 * 4);
    float* avgsum    = (float*)take(4);
    float* out_ws    = (float*)take((size_t)NN * 512 * 4);

    hipMemsetAsync(counts, 0, (size_t)NN * 4, stream);
    hipMemsetAsync(fill, 0, (size_t)NN * 4, stream);
    hipMemsetAsync(avgsum, 0, 4, stream);

    k_combine<<<1, 1024, 0, stream>>>(W_e, b_e, W_eo, b_eo, Wc, bc);
    k_prepw<<<512, 128, 0, stream>>>(W_no, Wcomb);
    k_node<<<(NN + 31) / 32, 128, 0, stream>>>(x, W_l, b_l, att, xl, ai, aj);
    k_count<<<(EE + 255) / 256, 256, 0, stream>>>(ei, counts);
    int nb = (NN + 1023) / 1024;
    k_scan1<<<nb, 1024, 0, stream>>>(counts, offsets, bsums, avgsum);
    k_scan2<<<1, 64, 0, stream>>>(bsums, nb);
    k_scan3<<<nb, 1024, 0, stream>>>(offsets, bsums);
    k_edge<<<(EE + 255) / 256, 256, 0, stream>>>(edge_attr, ei, W_e, b_e, att, Wc, bc,
                                                 ai, aj, offsets, fill,
                                                 csr_src, csr_logit, eout);
    k_aggr<<<(NN + 3) / 4, 256, 0, stream>>>(counts, offsets, csr_src, csr_logit,
                                             xl, out_ws);
    k_proj2<<<(NN + 63) / 64, 256, 0, stream>>>(out_ws, Wcomb, b_no, counts, avgsum, nout);
}

// Round 5
// 455.265 us; speedup vs baseline: 2.1999x; 1.1620x over previous
//
#include <hip/hip_runtime.h>
#include <hip/hip_bf16.h>

#define NN 50000
#define EE 800000
#define HH 2
#define CC 64
#define CEE 32

// ---------------- K0: combined edge weights: Wc = W_e @ W_eo, bc = b_e @ W_eo + b_eo
__global__ void k_combine(const float* __restrict__ We, const float* __restrict__ be,
                          const float* __restrict__ Weo, const float* __restrict__ beo,
                          float* __restrict__ Wc, float* __restrict__ bc) {
    int t = threadIdx.x;
    int i = t >> 5, j = t & 31;           // 32 x 32
    float s = 0.f;
    #pragma unroll
    for (int k = 0; k < 64; k++) s += We[i * 64 + k] * Weo[k * 32 + j];
    Wc[i * 32 + j] = s;
    if (t < 32) {
        float b = beo[t];
        #pragma unroll
        for (int k = 0; k < 64; k++) b += be[k] * Weo[k * 32 + t];
        bc[t] = b;
    }
}

// ---------------- K0b: projection weights combined: Wcomb[512][128]
__global__ void k_prepw(const float* __restrict__ Wno, float* __restrict__ Wcomb) {
    int r = blockIdx.x;        // 0..511  (= h*256 + agg*64 + c)
    int o = threadIdx.x;       // 0..127
    int h = r >> 8, q = r & 255;
    const float* base = Wno + (size_t)(h * 768 + q) * 64;
    float v;
    if (o < 64) v = base[o] + base[512 * 64 + o];
    else        v = base[256 * 64 + (o - 64)];
    Wcomb[r * 128 + o] = v;
}

// ---------------- K1: tiled GEMM xl = x @ W_l + b_l, fused ai/aj epilogue
__global__ __launch_bounds__(256) void k_node2(const float* __restrict__ x,
                                               const float* __restrict__ Wl,
                                               const float* __restrict__ bl,
                                               const float* __restrict__ att,
                                               float* __restrict__ xl,
                                               float* __restrict__ ai,
                                               float* __restrict__ aj) {
    __shared__ float sX[32][72];     // k-major x tile (64 nodes)
    __shared__ float sW[32][128];
    int t = threadIdx.x;
    int n0 = blockIdx.x * 64;
    int g = t & 31;                  // output col group: 4g..4g+3
    int ng = t >> 5;                 // node subgroup (8 nodes each)

    float acc[8][4];
    #pragma unroll
    for (int j = 0; j < 8; j++)
        #pragma unroll
        for (int q = 0; q < 4; q++) acc[j][q] = 0.f;

    int ldn = t >> 2;                // 0..63
    int ldk = (t & 3) * 8;           // 0,8,16,24
    int an = n0 + ldn; if (an >= NN) an = NN - 1;
    const float* Arow = x + (size_t)an * 128;
    int bk = t >> 3;                 // 0..31
    int bo = (t & 7) * 16;           // 0..112

    for (int kc = 0; kc < 128; kc += 32) {
        __syncthreads();
        float4 a0 = *(const float4*)(Arow + kc + ldk);
        float4 a1 = *(const float4*)(Arow + kc + ldk + 4);
        sX[ldk + 0][ldn] = a0.x; sX[ldk + 1][ldn] = a0.y;
        sX[ldk + 2][ldn] = a0.z; sX[ldk + 3][ldn] = a0.w;
        sX[ldk + 4][ldn] = a1.x; sX[ldk + 5][ldn] = a1.y;
        sX[ldk + 6][ldn] = a1.z; sX[ldk + 7][ldn] = a1.w;
        const float* bp = Wl + (size_t)(kc + bk) * 128 + bo;
        float4 b0 = *(const float4*)(bp);
        float4 b1 = *(const float4*)(bp + 4);
        float4 b2 = *(const float4*)(bp + 8);
        float4 b3 = *(const float4*)(bp + 12);
        *(float4*)&sW[bk][bo]      = b0;
        *(float4*)&sW[bk][bo + 4]  = b1;
        *(float4*)&sW[bk][bo + 8]  = b2;
        *(float4*)&sW[bk][bo + 12] = b3;
        __syncthreads();
        #pragma unroll 8
        for (int k = 0; k < 32; k++) {
            float4 b = *(const float4*)&sW[k][g * 4];
            float4 x0 = *(const float4*)&sX[k][ng * 8];
            float4 x1 = *(const float4*)&sX[k][ng * 8 + 4];
            float av[8] = {x0.x, x0.y, x0.z, x0.w, x1.x, x1.y, x1.z, x1.w};
            #pragma unroll
            for (int j = 0; j < 8; j++) {
                acc[j][0] += av[j] * b.x;
                acc[j][1] += av[j] * b.y;
                acc[j][2] += av[j] * b.z;
                acc[j][3] += av[j] * b.w;
            }
        }
    }

    // epilogue: +bias, write xl, leaky-relu, att-dot partials, butterfly
    float4 bv = *(const float4*)(bl + g * 4);
    int h = g >> 4;
    float atti[4], attj[4];
    #pragma unroll
    for (int q = 0; q < 4; q++) {
        int c = 4 * (g & 15) + q;
        atti[q] = att[h * 160 + c];
        attj[q] = att[h * 160 + 64 + c];
    }
    #pragma unroll
    for (int j = 0; j < 8; j++) {
        int n = n0 + ng * 8 + j;
        float v[4] = {acc[j][0] + bv.x, acc[j][1] + bv.y,
                      acc[j][2] + bv.z, acc[j][3] + bv.w};
        if (n < NN)
            *(float4*)(xl + (size_t)n * 128 + g * 4) = make_float4(v[0], v[1], v[2], v[3]);
        float sA = 0.f, sJ = 0.f;
        #pragma unroll
        for (int q = 0; q < 4; q++) {
            float lr = v[q] > 0.f ? v[q] : 0.2f * v[q];
            sA += lr * atti[q];
            sJ += lr * attj[q];
        }
        #pragma unroll
        for (int m = 1; m <= 8; m <<= 1) {
            sA += __shfl_xor(sA, m);
            sJ += __shfl_xor(sJ, m);
        }
        if ((g & 15) == 0 && n < NN) {
            ai[n * 2 + h] = sA;
            aj[n * 2 + h] = sJ;
        }
    }
}

// ---------------- K2a: degree counts over dst
__global__ void k_count(const int* __restrict__ ei, int* __restrict__ counts) {
    int e = blockIdx.x * 256 + threadIdx.x;
    if (e < EE) atomicAdd(&counts[ei[EE + e]], 1);
}

// ---------------- scan (3 kernels); k_scan1 also folds in avg_log accumulation
__global__ __launch_bounds__(1024) void k_scan1(const int* __restrict__ counts,
                                                int* __restrict__ offsets,
                                                int* __restrict__ bsums,
                                                float* __restrict__ avgsum) {
    __shared__ int s[1024];
    int g = blockIdx.x * 1024 + threadIdx.x;
    int v = (g < NN) ? counts[g] : 0;
    s[threadIdx.x] = v;
    __syncthreads();
    for (int st = 1; st < 1024; st <<= 1) {
        int t = (threadIdx.x >= st) ? s[threadIdx.x - st] : 0;
        __syncthreads();
        s[threadIdx.x] += t;
        __syncthreads();
    }
    if (g < NN) offsets[g] = s[threadIdx.x] - v;
    if (threadIdx.x == 1023) bsums[blockIdx.x] = s[1023];
    float lv = (g < NN) ? logf((float)v + 1.0f) : 0.0f;
    #pragma unroll
    for (int m = 32; m; m >>= 1) lv += __shfl_xor(lv, m);
    if ((threadIdx.x & 63) == 0) atomicAdd(avgsum, lv);
}

__global__ void k_scan2(int* __restrict__ bsums, int nb) {
    if (threadIdx.x == 0 && blockIdx.x == 0) {
        int c = 0;
        for (int i = 0; i < nb; i++) { int t = bsums[i]; bsums[i] = c; c += t; }
    }
}

__global__ __launch_bounds__(1024) void k_scan3(int* __restrict__ offsets,
                                                const int* __restrict__ bsums) {
    int g = blockIdx.x * 1024 + threadIdx.x;
    if (g < NN) offsets[g] += bsums[blockIdx.x];
}

// ---------------- K3: edge pass, lane = output column, weights in registers.
// 64 edges per block (EE % 64 == 0), 16 edges per wave.
__global__ __launch_bounds__(256) void k_edge2(const float* __restrict__ ea,
                                               const int* __restrict__ ei,
                                               const float* __restrict__ We,
                                               const float* __restrict__ be,
                                               const float* __restrict__ att,
                                               const float* __restrict__ Wc,
                                               const float* __restrict__ bc,
                                               const float* __restrict__ ai,
                                               const float* __restrict__ aj,
                                               const int* __restrict__ offsets,
                                               int* __restrict__ fill,
                                               int* __restrict__ csr_src,
                                               float* __restrict__ csr_logit,
                                               float* __restrict__ eout) {
    __shared__ float sA[64][36];     // 36-pad: <=2-way write aliasing, 16B-aligned rows
    int t = threadIdx.x;
    int wave = t >> 6, lane = t & 63;
    int e0 = blockIdx.x * 64;

    // stage 64 edges x 32 attrs (coalesced 2KB/wave)
    {
        int le = t >> 2, lk = (t & 3) * 8;
        const float4* p = (const float4*)(ea + (size_t)(e0 + le) * 32 + lk);
        float4 f0 = p[0], f1 = p[1];
        *(float4*)&sA[le][lk]     = f0;
        *(float4*)&sA[le][lk + 4] = f1;
    }

    // per-lane register weights: lane = m column of We (64 cols)
    float wl[32];
    #pragma unroll
    for (int k = 0; k < 32; k++) wl[k] = We[k * 64 + lane];
    float sbe_l  = be[lane];
    float satt_l = att[(lane >> 5) * 160 + 128 + (lane & 31)];
    float wc[32];
    #pragma unroll
    for (int k = 0; k < 32; k++) wc[k] = Wc[k * 32 + (lane & 31)];
    float bc_l = bc[lane & 31];

    // per-edge metadata (16 edges per wave; lanes replicate x4)
    int ew0 = e0 + wave * 16;
    int eidx = ew0 + (lane & 15);
    int msrc = ei[eidx], mdst = ei[EE + eidx];
    float2 aiv = *(const float2*)(ai + (size_t)mdst * 2);
    float2 ajv = *(const float2*)(aj + (size_t)msrc * 2);

    __syncthreads();

    // ---- logits: serial over 16 edges, all 64 lanes = 64 m-columns
    float myLg0 = 0.f, myLg1 = 0.f;
    for (int i = 0; i < 16; i++) {
        const float* ap = &sA[wave * 16 + i][0];
        float s = sbe_l;
        #pragma unroll
        for (int k = 0; k < 32; k++) s += ap[k] * wl[k];
        float lr = s > 0.f ? s : 0.2f * s;
        float cb = lr * satt_l;
        #pragma unroll
        for (int m = 1; m <= 16; m <<= 1) cb += __shfl_xor(cb, m);
        float other = __shfl_xor(cb, 32);
        float h0 = (lane < 32) ? cb : other;
        float h1 = (lane < 32) ? other : cb;
        if ((lane & 15) == i) { myLg0 = h0; myLg1 = h1; }
    }
    if (lane < 16) {
        float lg0 = myLg0 + aiv.x + ajv.x;
        float lg1 = myLg1 + aiv.y + ajv.y;
        int pos = offsets[mdst] + atomicAdd(&fill[mdst], 1);
        csr_src[pos] = msrc;
        *(float2*)(csr_logit + (size_t)pos * 2) = make_float2(lg0, lg1);
    }

    // ---- eout: 2 edges per pass (lane halves), 8 passes
    #pragma unroll 2
    for (int pr = 0; pr < 8; pr++) {
        int el = wave * 16 + pr * 2 + (lane >> 5);
        const float* ap = &sA[el][0];
        float s = bc_l;
        #pragma unroll
        for (int k = 0; k < 32; k++) s += ap[k] * wc[k];
        eout[(size_t)(e0 + el) * 32 + (lane & 31)] = s;
    }
}

// ---------------- K4: one wave per NODE, both heads fused.
__global__ __launch_bounds__(256) void k_aggr(const int* __restrict__ counts,
                                              const int* __restrict__ offsets,
                                              const int* __restrict__ csr_src,
                                              const float* __restrict__ csr_logit,
                                              const float* __restrict__ xl,
                                              float* __restrict__ out_ws) {
    int lane = threadIdx.x & 63;
    int wv = threadIdx.x >> 6;
    int n = blockIdx.x * 4 + wv;
    if (n >= NN) return;
    int deg = counts[n], start = offsets[n];

    float sum0 = 0.f, sum1 = 0.f, sq0 = 0.f, sq1 = 0.f;
    float mn0 = 1e30f, mn1 = 1e30f, mx0 = -1e30f, mx1 = -1e30f;

    if (deg > 0 && deg <= 64) {
        float2 lg = make_float2(-1e30f, -1e30f);
        int srcv = 0;
        if (lane < deg) {
            lg = *(const float2*)(csr_logit + (size_t)(start + lane) * 2);
            srcv = csr_src[start + lane];
        }
        float m0 = lg.x, m1 = lg.y;
        #pragma unroll
        for (int s = 32; s; s >>= 1) {
            m0 = fmaxf(m0, __shfl_xor(m0, s));
            m1 = fmaxf(m1, __shfl_xor(m1, s));
        }
        float e0 = (lane < deg) ? __expf(lg.x - m0) : 0.f;
        float e1 = (lane < deg) ? __expf(lg.y - m1) : 0.f;
        float s0 = e0, s1 = e1;
        #pragma unroll
        for (int s = 32; s; s >>= 1) {
            s0 += __shfl_xor(s0, s);
            s1 += __shfl_xor(s1, s);
        }
        float a0 = e0 / (s0 + 1e-16f);
        float a1 = e1 / (s1 + 1e-16f);

        for (int i = 0; i < deg; i++) {
            int sidx = __shfl(srcv, i);
            float al0 = __shfl(a0, i);
            float al1 = __shfl(a1, i);
            float alpha = (lane < 32) ? al0 : al1;
            float2 v = *(const float2*)(xl + (size_t)sidx * 128 + lane * 2);
            float g0 = v.x * alpha, g1 = v.y * alpha;
            sum0 += g0; sum1 += g1;
            sq0 += g0 * g0; sq1 += g1 * g1;
            mn0 = fminf(mn0, g0); mn1 = fminf(mn1, g1);
            mx0 = fmaxf(mx0, g0); mx1 = fmaxf(mx1, g1);
        }
    } else if (deg > 64) {
        float m0 = -1e30f, m1 = -1e30f;
        for (int i = lane; i < deg; i += 64) {
            float2 lg = *(const float2*)(csr_logit + (size_t)(start + i) * 2);
            m0 = fmaxf(m0, lg.x); m1 = fmaxf(m1, lg.y);
        }
        #pragma unroll
        for (int s = 32; s; s >>= 1) {
            m0 = fmaxf(m0, __shfl_xor(m0, s));
            m1 = fmaxf(m1, __shfl_xor(m1, s));
        }
        float s0 = 0.f, s1 = 0.f;
        for (int i = lane; i < deg; i += 64) {
            float2 lg = *(const float2*)(csr_logit + (size_t)(start + i) * 2);
            s0 += __expf(lg.x - m0); s1 += __expf(lg.y - m1);
        }
        #pragma unroll
        for (int s = 32; s; s >>= 1) {
            s0 += __shfl_xor(s0, s);
            s1 += __shfl_xor(s1, s);
        }
        float inv0 = 1.0f / (s0 + 1e-16f), inv1 = 1.0f / (s1 + 1e-16f);
        for (int i = 0; i < deg; i++) {
            float2 lg = *(const float2*)(csr_logit + (size_t)(start + i) * 2);
            int sidx = csr_src[start + i];
            float al0 = __expf(lg.x - m0) * inv0;
            float al1 = __expf(lg.y - m1) * inv1;
            float alpha = (lane < 32) ? al0 : al1;
            float2 v = *(const float2*)(xl + (size_t)sidx * 128 + lane * 2);
            float g0 = v.x * alpha, g1 = v.y * alpha;
            sum0 += g0; sum1 += g1;
            sq0 += g0 * g0; sq1 += g1 * g1;
            mn0 = fminf(mn0, g0); mn1 = fminf(mn1, g1);
            mx0 = fmaxf(mx0, g0); mx1 = fmaxf(mx1, g1);
        }
    } else {
        mn0 = mn1 = mx0 = mx1 = 0.f;
    }

    float cc = deg > 0 ? (float)deg : 1.0f;
    float mean0 = sum0 / cc, mean1 = sum1 / cc;
    float sd0 = sqrtf(fmaxf(sq0 / cc - mean0 * mean0, 0.0f) + 1e-5f);
    float sd1 = sqrtf(fmaxf(sq1 / cc - mean1 * mean1, 0.0f) + 1e-5f);

    int c2 = lane * 2, h = c2 >> 6, c = c2 & 63;
    float* ob = out_ws + (size_t)n * 512 + h * 256 + c;
    *(float2*)(ob + 0)   = make_float2(mean0, mean1);
    *(float2*)(ob + 64)  = make_float2(mn0, mn1);
    *(float2*)(ob + 128) = make_float2(mx0, mx1);
    *(float2*)(ob + 192) = make_float2(sd0, sd1);
}

// ---------------- K5: tiled fp32 GEMM  out = A[N,512] @ Wcomb[512,128]
__global__ __launch_bounds__(256) void k_proj2(const float* __restrict__ A,
                                               const float* __restrict__ Wcomb,
                                               const float* __restrict__ bno,
                                               const int* __restrict__ counts,
                                               const float* __restrict__ avgsum,
                                               float* __restrict__ nout) {
    __shared__ float sA[32][72];
    __shared__ float sB[32][128];
    int t = threadIdx.x;
    int n0 = blockIdx.x * 64;
    int g = t & 31;
    int ng = t >> 5;

    float acc[8][4];
    #pragma unroll
    for (int j = 0; j < 8; j++)
        #pragma unroll
        for (int q = 0; q < 4; q++) acc[j][q] = 0.f;

    int ldn = t >> 2;
    int ldk = (t & 3) * 8;
    int an = n0 + ldn; if (an >= NN) an = NN - 1;
    const float* Arow = A + (size_t)an * 512;
    int bk = t >> 3;
    int bo = (t & 7) * 16;

    for (int kc = 0; kc < 512; kc += 32) {
        __syncthreads();
        float4 a0 = *(const float4*)(Arow + kc + ldk);
        float4 a1 = *(const float4*)(Arow + kc + ldk + 4);
        sA[ldk + 0][ldn] = a0.x; sA[ldk + 1][ldn] = a0.y;
        sA[ldk + 2][ldn] = a0.z; sA[ldk + 3][ldn] = a0.w;
        sA[ldk + 4][ldn] = a1.x; sA[ldk + 5][ldn] = a1.y;
        sA[ldk + 6][ldn] = a1.z; sA[ldk + 7][ldn] = a1.w;
        const float* bp = Wcomb + (size_t)(kc + bk) * 128 + bo;
        float4 b0 = *(const float4*)(bp);
        float4 b1 = *(const float4*)(bp + 4);
        float4 b2 = *(const float4*)(bp + 8);
        float4 b3 = *(const float4*)(bp + 12);
        *(float4*)&sB[bk][bo]      = b0;
        *(float4*)&sB[bk][bo + 4]  = b1;
        *(float4*)&sB[bk][bo + 8]  = b2;
        *(float4*)&sB[bk][bo + 12] = b3;
        __syncthreads();
        #pragma unroll 8
        for (int k = 0; k < 32; k++) {
            float4 b = *(const float4*)&sB[k][g * 4];
            float4 x0 = *(const float4*)&sA[k][ng * 8];
            float4 x1 = *(const float4*)&sA[k][ng * 8 + 4];
            float av[8] = {x0.x, x0.y, x0.z, x0.w, x1.x, x1.y, x1.z, x1.w};
            #pragma unroll
            for (int j = 0; j < 8; j++) {
                acc[j][0] += av[j] * b.x;
                acc[j][1] += av[j] * b.y;
                acc[j][2] += av[j] * b.z;
                acc[j][3] += av[j] * b.w;
            }
        }
    }

    float avg_log = *avgsum / (float)NN;
    float4 bv = *(const float4*)(bno + (g & 15) * 4);
    #pragma unroll
    for (int j = 0; j < 8; j++) {
        int n = n0 + ng * 8 + j;
        float p0 = __shfl_xor(acc[j][0], 16);
        float p1 = __shfl_xor(acc[j][1], 16);
        float p2 = __shfl_xor(acc[j][2], 16);
        float p3 = __shfl_xor(acc[j][3], 16);
        if (g < 16 && n < NN) {
            float cnt = (float)counts[n];
            float ld = logf(fmaxf(cnt, 1.0f) + 1.0f);
            float s1 = ld / avg_log;
            float4 o;
            o.x = acc[j][0] + s1 * p0 + bv.x;
            o.y = acc[j][1] + s1 * p1 + bv.y;
            o.z = acc[j][2] + s1 * p2 + bv.z;
            o.w = acc[j][3] + s1 * p3 + bv.w;
            *(float4*)(nout + (size_t)n * 64 + g * 4) = o;
        }
    }
}

extern "C" void kernel_launch(void* const* d_in, const int* in_sizes, int n_in,
                              void* d_out, int out_size, void* d_ws, size_t ws_size,
                              hipStream_t stream) {
    const float* x         = (const float*)d_in[0];
    const float* edge_attr = (const float*)d_in[1];
    const int*   ei        = (const int*)d_in[2];
    const float* W_l       = (const float*)d_in[3];
    const float* b_l       = (const float*)d_in[4];
    const float* W_e       = (const float*)d_in[5];
    const float* b_e       = (const float*)d_in[6];
    const float* att       = (const float*)d_in[7];
    const float* W_no      = (const float*)d_in[8];
    const float* b_no      = (const float*)d_in[9];
    const float* W_eo      = (const float*)d_in[10];
    const float* b_eo      = (const float*)d_in[11];

    float* nout = (float*)d_out;                    // [N, 64]
    float* eout = (float*)d_out + (size_t)NN * 64;  // [E, 32]

    char* ws = (char*)d_ws;
    size_t off = 0;
    auto take = [&](size_t bytes) -> char* {
        char* p = ws + off;
        off = (off + bytes + 255) & ~(size_t)255;
        return p;
    };
    float* xl        = (float*)take((size_t)NN * 128 * 4);
    float* ai        = (float*)take((size_t)NN * 2 * 4);
    float* aj        = (float*)take((size_t)NN * 2 * 4);
    float* csr_logit = (float*)take((size_t)EE * 2 * 4);
    int*   csr_src   = (int*)take((size_t)EE * 4);
    int*   counts    = (int*)take((size_t)NN * 4);
    int*   offsets   = (int*)take((size_t)NN * 4);
    int*   fill      = (int*)take((size_t)NN * 4);
    int*   bsums     = (int*)take(256 * 4);
    float* Wc        = (float*)take(32 * 32 * 4);
    float* bc        = (float*)take(32 * 4);
    float* Wcomb     = (float*)take(512 * 128 * 4);
    float* avgsum    = (float*)take(4);
    float* out_ws    = (float*)take((size_t)NN * 512 * 4);

    hipMemsetAsync(counts, 0, (size_t)NN * 4, stream);
    hipMemsetAsync(fill, 0, (size_t)NN * 4, stream);
    hipMemsetAsync(avgsum, 0, 4, stream);

    k_combine<<<1, 1024, 0, stream>>>(W_e, b_e, W_eo, b_eo, Wc, bc);
    k_prepw<<<512, 128, 0, stream>>>(W_no, Wcomb);
    k_node2<<<(NN + 63) / 64, 256, 0, stream>>>(x, W_l, b_l, att, xl, ai, aj);
    k_count<<<(EE + 255) / 256, 256, 0, stream>>>(ei, counts);
    int nb = (NN + 1023) / 1024;
    k_scan1<<<nb, 1024, 0, stream>>>(counts, offsets, bsums, avgsum);
    k_scan2<<<1, 64, 0, stream>>>(bsums, nb);
    k_scan3<<<nb, 1024, 0, stream>>>(offsets, bsums);
    k_edge2<<<EE / 64, 256, 0, stream>>>(edge_attr, ei, W_e, b_e, att, Wc, bc,
                                         ai, aj, offsets, fill,
                                         csr_src, csr_logit, eout);
    k_aggr<<<(NN + 3) / 4, 256, 0, stream>>>(counts, offsets, csr_src, csr_logit,
                                             xl, out_ws);
    k_proj2<<<(NN + 63) / 64, 256, 0, stream>>>(out_ws, Wcomb, b_no, counts, avgsum, nout);
}

// Round 6
// 430.859 us; speedup vs baseline: 2.3245x; 1.0566x over previous
//
#include <hip/hip_runtime.h>
#include <hip/hip_bf16.h>

#define NN 50000
#define EE 800000
#define HH 2
#define CC 64
#define CEE 32

typedef __attribute__((ext_vector_type(8))) short bf16x8;
typedef __attribute__((ext_vector_type(4))) float f32x4;

__device__ __forceinline__ short f2bf(float f) {
    union { float f; unsigned u; } v; v.f = f;
    unsigned r = v.u + 0x7FFF + ((v.u >> 16) & 1);   // RNE
    return (short)(r >> 16);
}

// ---------------- K0: combined edge weights: Wc = W_e @ W_eo, bc = b_e @ W_eo + b_eo
__global__ void k_combine(const float* __restrict__ We, const float* __restrict__ be,
                          const float* __restrict__ Weo, const float* __restrict__ beo,
                          float* __restrict__ Wc, float* __restrict__ bc) {
    int t = threadIdx.x;
    int i = t >> 5, j = t & 31;           // 32 x 32
    float s = 0.f;
    #pragma unroll
    for (int k = 0; k < 64; k++) s += We[i * 64 + k] * Weo[k * 32 + j];
    Wc[i * 32 + j] = s;
    if (t < 32) {
        float b = beo[t];
        #pragma unroll
        for (int k = 0; k < 64; k++) b += be[k] * Weo[k * 32 + t];
        bc[t] = b;
    }
}

// ---------------- K0b: projection weights combined: Wcomb[512][128]
__global__ void k_prepw(const float* __restrict__ Wno, float* __restrict__ Wcomb) {
    int r = blockIdx.x;        // 0..511  (= h*256 + agg*64 + c)
    int o = threadIdx.x;       // 0..127
    int h = r >> 8, q = r & 255;
    const float* base = Wno + (size_t)(h * 768 + q) * 64;
    float v;
    if (o < 64) v = base[o] + base[512 * 64 + o];
    else        v = base[256 * 64 + (o - 64)];
    Wcomb[r * 128 + o] = v;
}

// ---------------- K1: tiled GEMM xl = x @ W_l + b_l, fused ai/aj epilogue
__global__ __launch_bounds__(256) void k_node2(const float* __restrict__ x,
                                               const float* __restrict__ Wl,
                                               const float* __restrict__ bl,
                                               const float* __restrict__ att,
                                               float* __restrict__ xl,
                                               float* __restrict__ ai,
                                               float* __restrict__ aj) {
    __shared__ float sX[32][72];     // k-major x tile (64 nodes)
    __shared__ float sW[32][128];
    int t = threadIdx.x;
    int n0 = blockIdx.x * 64;
    int g = t & 31;                  // output col group: 4g..4g+3
    int ng = t >> 5;                 // node subgroup (8 nodes each)

    float acc[8][4];
    #pragma unroll
    for (int j = 0; j < 8; j++)
        #pragma unroll
        for (int q = 0; q < 4; q++) acc[j][q] = 0.f;

    int ldn = t >> 2;                // 0..63
    int ldk = (t & 3) * 8;           // 0,8,16,24
    int an = n0 + ldn; if (an >= NN) an = NN - 1;
    const float* Arow = x + (size_t)an * 128;
    int bk = t >> 3;                 // 0..31
    int bo = (t & 7) * 16;           // 0..112

    for (int kc = 0; kc < 128; kc += 32) {
        __syncthreads();
        float4 a0 = *(const float4*)(Arow + kc + ldk);
        float4 a1 = *(const float4*)(Arow + kc + ldk + 4);
        sX[ldk + 0][ldn] = a0.x; sX[ldk + 1][ldn] = a0.y;
        sX[ldk + 2][ldn] = a0.z; sX[ldk + 3][ldn] = a0.w;
        sX[ldk + 4][ldn] = a1.x; sX[ldk + 5][ldn] = a1.y;
        sX[ldk + 6][ldn] = a1.z; sX[ldk + 7][ldn] = a1.w;
        const float* bp = Wl + (size_t)(kc + bk) * 128 + bo;
        float4 b0 = *(const float4*)(bp);
        float4 b1 = *(const float4*)(bp + 4);
        float4 b2 = *(const float4*)(bp + 8);
        float4 b3 = *(const float4*)(bp + 12);
        *(float4*)&sW[bk][bo]      = b0;
        *(float4*)&sW[bk][bo + 4]  = b1;
        *(float4*)&sW[bk][bo + 8]  = b2;
        *(float4*)&sW[bk][bo + 12] = b3;
        __syncthreads();
        #pragma unroll 8
        for (int k = 0; k < 32; k++) {
            float4 b = *(const float4*)&sW[k][g * 4];
            float4 x0 = *(const float4*)&sX[k][ng * 8];
            float4 x1 = *(const float4*)&sX[k][ng * 8 + 4];
            float av[8] = {x0.x, x0.y, x0.z, x0.w, x1.x, x1.y, x1.z, x1.w};
            #pragma unroll
            for (int j = 0; j < 8; j++) {
                acc[j][0] += av[j] * b.x;
                acc[j][1] += av[j] * b.y;
                acc[j][2] += av[j] * b.z;
                acc[j][3] += av[j] * b.w;
            }
        }
    }

    float4 bv = *(const float4*)(bl + g * 4);
    int h = g >> 4;
    float atti[4], attj[4];
    #pragma unroll
    for (int q = 0; q < 4; q++) {
        int c = 4 * (g & 15) + q;
        atti[q] = att[h * 160 + c];
        attj[q] = att[h * 160 + 64 + c];
    }
    #pragma unroll
    for (int j = 0; j < 8; j++) {
        int n = n0 + ng * 8 + j;
        float v[4] = {acc[j][0] + bv.x, acc[j][1] + bv.y,
                      acc[j][2] + bv.z, acc[j][3] + bv.w};
        if (n < NN)
            *(float4*)(xl + (size_t)n * 128 + g * 4) = make_float4(v[0], v[1], v[2], v[3]);
        float sA = 0.f, sJ = 0.f;
        #pragma unroll
        for (int q = 0; q < 4; q++) {
            float lr = v[q] > 0.f ? v[q] : 0.2f * v[q];
            sA += lr * atti[q];
            sJ += lr * attj[q];
        }
        #pragma unroll
        for (int m = 1; m <= 8; m <<= 1) {
            sA += __shfl_xor(sA, m);
            sJ += __shfl_xor(sJ, m);
        }
        if ((g & 15) == 0 && n < NN) {
            ai[n * 2 + h] = sA;
            aj[n * 2 + h] = sJ;
        }
    }
}

// ---------------- K2a: degree counts over dst
__global__ void k_count(const int* __restrict__ ei, int* __restrict__ counts) {
    int e = blockIdx.x * 256 + threadIdx.x;
    if (e < EE) atomicAdd(&counts[ei[EE + e]], 1);
}

// ---------------- scan (3 kernels); k_scan1 also folds in avg_log accumulation
__global__ __launch_bounds__(1024) void k_scan1(const int* __restrict__ counts,
                                                int* __restrict__ offsets,
                                                int* __restrict__ bsums,
                                                float* __restrict__ avgsum) {
    __shared__ int s[1024];
    int g = blockIdx.x * 1024 + threadIdx.x;
    int v = (g < NN) ? counts[g] : 0;
    s[threadIdx.x] = v;
    __syncthreads();
    for (int st = 1; st < 1024; st <<= 1) {
        int t = (threadIdx.x >= st) ? s[threadIdx.x - st] : 0;
        __syncthreads();
        s[threadIdx.x] += t;
        __syncthreads();
    }
    if (g < NN) offsets[g] = s[threadIdx.x] - v;
    if (threadIdx.x == 1023) bsums[blockIdx.x] = s[1023];
    float lv = (g < NN) ? logf((float)v + 1.0f) : 0.0f;
    #pragma unroll
    for (int m = 32; m; m >>= 1) lv += __shfl_xor(lv, m);
    if ((threadIdx.x & 63) == 0) atomicAdd(avgsum, lv);
}

__global__ void k_scan2(int* __restrict__ bsums, int nb) {
    if (threadIdx.x == 0 && blockIdx.x == 0) {
        int c = 0;
        for (int i = 0; i < nb; i++) { int t = bsums[i]; bsums[i] = c; c += t; }
    }
}

__global__ __launch_bounds__(1024) void k_scan3(int* __restrict__ offsets,
                                                const int* __restrict__ bsums) {
    int g = blockIdx.x * 1024 + threadIdx.x;
    if (g < NN) offsets[g] += bsums[blockIdx.x];
}

// ---------------- K3: MFMA edge pass. Per wave-step: 16 edges.
// B-frag = edge attrs (K=32 x N=16 edges, bf16). A-frags = We^T (4 m-blocks),
// Wc^T (2 c-blocks), weights register-resident; biases folded into C-operand.
// D layout (verified, guide §3): col=lane&15 (edge), row=(lane>>4)*4+reg (+16*blk).
__global__ __launch_bounds__(256) void k_edge3(const float* __restrict__ ea,
                                               const int* __restrict__ ei,
                                               const float* __restrict__ We,
                                               const float* __restrict__ be,
                                               const float* __restrict__ att,
                                               const float* __restrict__ Wc,
                                               const float* __restrict__ bc,
                                               const float* __restrict__ ai,
                                               const float* __restrict__ aj,
                                               const int* __restrict__ offsets,
                                               int* __restrict__ fill,
                                               int* __restrict__ csr_src,
                                               float* __restrict__ csr_logit,
                                               float* __restrict__ eout) {
    int t = threadIdx.x;
    int lane = t & 63, wave = t >> 6;
    int l15 = lane & 15, lq = lane >> 4;

    // A-frags: A[row][k], lane: row=l15(+16*blk), k=lq*8+j
    bf16x8 aWe[4], aWc[2];
    #pragma unroll
    for (int mb = 0; mb < 4; mb++)
        #pragma unroll
        for (int j = 0; j < 8; j++)
            aWe[mb][j] = f2bf(We[(lq * 8 + j) * 64 + mb * 16 + l15]);
    #pragma unroll
    for (int cb = 0; cb < 2; cb++)
        #pragma unroll
        for (int j = 0; j < 8; j++)
            aWc[cb][j] = f2bf(Wc[(lq * 8 + j) * 32 + cb * 16 + l15]);

    // per-lane bias/att for accumulator rows
    f32x4 beC[4], bcC[2];
    float attR[4][4];
    #pragma unroll
    for (int mb = 0; mb < 4; mb++)
        #pragma unroll
        for (int r = 0; r < 4; r++) {
            int m = mb * 16 + lq * 4 + r;
            beC[mb][r] = be[m];
            attR[mb][r] = att[(m >> 5) * 160 + 128 + (m & 31)];
        }
    #pragma unroll
    for (int cb = 0; cb < 2; cb++)
        #pragma unroll
        for (int r = 0; r < 4; r++)
            bcC[cb][r] = bc[cb * 16 + lq * 4 + r];

    // 4 groups of 16 edges per wave -> 256 edges per block
    #pragma unroll 1
    for (int g = 0; g < 4; g++) {
        int e0 = blockIdx.x * 256 + wave * 64 + g * 16;
        int e = e0 + l15;

        // B-frag: ea[e][lq*8 .. lq*8+7]  (wave covers 16 edges x 32 attrs, coalesced)
        const float4* p = (const float4*)(ea + (size_t)e * 32 + lq * 8);
        float4 f0 = p[0], f1 = p[1];
        bf16x8 bE;
        bE[0] = f2bf(f0.x); bE[1] = f2bf(f0.y); bE[2] = f2bf(f0.z); bE[3] = f2bf(f0.w);
        bE[4] = f2bf(f1.x); bE[5] = f2bf(f1.y); bE[6] = f2bf(f1.z); bE[7] = f2bf(f1.w);

        // logits: m = lrelu(ea@We + be); per-head att dot
        float p0 = 0.f, p1 = 0.f;
        #pragma unroll
        for (int mb = 0; mb < 4; mb++) {
            f32x4 acc = __builtin_amdgcn_mfma_f32_16x16x32_bf16(aWe[mb], bE, beC[mb], 0, 0, 0);
            float ps = 0.f;
            #pragma unroll
            for (int r = 0; r < 4; r++) {
                float m = acc[r];
                float lr = m > 0.f ? m : 0.2f * m;
                ps += lr * attR[mb][r];
            }
            if (mb < 2) p0 += ps; else p1 += ps;
        }
        p0 += __shfl_xor(p0, 16); p0 += __shfl_xor(p0, 32);
        p1 += __shfl_xor(p1, 16); p1 += __shfl_xor(p1, 32);

        if (lane < 16) {
            int msrc = ei[e], mdst = ei[EE + e];
            float2 aiv = *(const float2*)(ai + (size_t)mdst * 2);
            float2 ajv = *(const float2*)(aj + (size_t)msrc * 2);
            float lg0 = p0 + aiv.x + ajv.x;
            float lg1 = p1 + aiv.y + ajv.y;
            int pos = offsets[mdst] + atomicAdd(&fill[mdst], 1);
            csr_src[pos] = msrc;
            *(float2*)(csr_logit + (size_t)pos * 2) = make_float2(lg0, lg1);
        }

        // eout = ea@Wc + bc  (straight from accumulator)
        #pragma unroll
        for (int cb = 0; cb < 2; cb++) {
            f32x4 oc = __builtin_amdgcn_mfma_f32_16x16x32_bf16(aWc[cb], bE, bcC[cb], 0, 0, 0);
            *(float4*)(eout + (size_t)e * 32 + cb * 16 + lq * 4) =
                make_float4(oc[0], oc[1], oc[2], oc[3]);
        }
    }
}

// ---------------- K4: one wave per NODE, both heads fused.
__global__ __launch_bounds__(256) void k_aggr(const int* __restrict__ counts,
                                              const int* __restrict__ offsets,
                                              const int* __restrict__ csr_src,
                                              const float* __restrict__ csr_logit,
                                              const float* __restrict__ xl,
                                              float* __restrict__ out_ws) {
    int lane = threadIdx.x & 63;
    int wv = threadIdx.x >> 6;
    int n = blockIdx.x * 4 + wv;
    if (n >= NN) return;
    int deg = counts[n], start = offsets[n];

    float sum0 = 0.f, sum1 = 0.f, sq0 = 0.f, sq1 = 0.f;
    float mn0 = 1e30f, mn1 = 1e30f, mx0 = -1e30f, mx1 = -1e30f;

    if (deg > 0 && deg <= 64) {
        float2 lg = make_float2(-1e30f, -1e30f);
        int srcv = 0;
        if (lane < deg) {
            lg = *(const float2*)(csr_logit + (size_t)(start + lane) * 2);
            srcv = csr_src[start + lane];
        }
        float m0 = lg.x, m1 = lg.y;
        #pragma unroll
        for (int s = 32; s; s >>= 1) {
            m0 = fmaxf(m0, __shfl_xor(m0, s));
            m1 = fmaxf(m1, __shfl_xor(m1, s));
        }
        float e0 = (lane < deg) ? __expf(lg.x - m0) : 0.f;
        float e1 = (lane < deg) ? __expf(lg.y - m1) : 0.f;
        float s0 = e0, s1 = e1;
        #pragma unroll
        for (int s = 32; s; s >>= 1) {
            s0 += __shfl_xor(s0, s);
            s1 += __shfl_xor(s1, s);
        }
        float a0 = e0 / (s0 + 1e-16f);
        float a1 = e1 / (s1 + 1e-16f);

        for (int i = 0; i < deg; i++) {
            int sidx = __shfl(srcv, i);
            float al0 = __shfl(a0, i);
            float al1 = __shfl(a1, i);
            float alpha = (lane < 32) ? al0 : al1;
            float2 v = *(const float2*)(xl + (size_t)sidx * 128 + lane * 2);
            float g0 = v.x * alpha, g1 = v.y * alpha;
            sum0 += g0; sum1 += g1;
            sq0 += g0 * g0; sq1 += g1 * g1;
            mn0 = fminf(mn0, g0); mn1 = fminf(mn1, g1);
            mx0 = fmaxf(mx0, g0); mx1 = fmaxf(mx1, g1);
        }
    } else if (deg > 64) {
        float m0 = -1e30f, m1 = -1e30f;
        for (int i = lane; i < deg; i += 64) {
            float2 lg = *(const float2*)(csr_logit + (size_t)(start + i) * 2);
            m0 = fmaxf(m0, lg.x); m1 = fmaxf(m1, lg.y);
        }
        #pragma unroll
        for (int s = 32; s; s >>= 1) {
            m0 = fmaxf(m0, __shfl_xor(m0, s));
            m1 = fmaxf(m1, __shfl_xor(m1, s));
        }
        float s0 = 0.f, s1 = 0.f;
        for (int i = lane; i < deg; i += 64) {
            float2 lg = *(const float2*)(csr_logit + (size_t)(start + i) * 2);
            s0 += __expf(lg.x - m0); s1 += __expf(lg.y - m1);
        }
        #pragma unroll
        for (int s = 32; s; s >>= 1) {
            s0 += __shfl_xor(s0, s);
            s1 += __shfl_xor(s1, s);
        }
        float inv0 = 1.0f / (s0 + 1e-16f), inv1 = 1.0f / (s1 + 1e-16f);
        for (int i = 0; i < deg; i++) {
            float2 lg = *(const float2*)(csr_logit + (size_t)(start + i) * 2);
            int sidx = csr_src[start + i];
            float al0 = __expf(lg.x - m0) * inv0;
            float al1 = __expf(lg.y - m1) * inv1;
            float alpha = (lane < 32) ? al0 : al1;
            float2 v = *(const float2*)(xl + (size_t)sidx * 128 + lane * 2);
            float g0 = v.x * alpha, g1 = v.y * alpha;
            sum0 += g0; sum1 += g1;
            sq0 += g0 * g0; sq1 += g1 * g1;
            mn0 = fminf(mn0, g0); mn1 = fminf(mn1, g1);
            mx0 = fmaxf(mx0, g0); mx1 = fmaxf(mx1, g1);
        }
    } else {
        mn0 = mn1 = mx0 = mx1 = 0.f;
    }

    float cc = deg > 0 ? (float)deg : 1.0f;
    float mean0 = sum0 / cc, mean1 = sum1 / cc;
    float sd0 = sqrtf(fmaxf(sq0 / cc - mean0 * mean0, 0.0f) + 1e-5f);
    float sd1 = sqrtf(fmaxf(sq1 / cc - mean1 * mean1, 0.0f) + 1e-5f);

    int c2 = lane * 2, h = c2 >> 6, c = c2 & 63;
    float* ob = out_ws + (size_t)n * 512 + h * 256 + c;
    *(float2*)(ob + 0)   = make_float2(mean0, mean1);
    *(float2*)(ob + 64)  = make_float2(mn0, mn1);
    *(float2*)(ob + 128) = make_float2(mx0, mx1);
    *(float2*)(ob + 192) = make_float2(sd0, sd1);
}

// ---------------- K5: tiled fp32 GEMM  out = A[N,512] @ Wcomb[512,128]
__global__ __launch_bounds__(256) void k_proj2(const float* __restrict__ A,
                                               const float* __restrict__ Wcomb,
                                               const float* __restrict__ bno,
                                               const int* __restrict__ counts,
                                               const float* __restrict__ avgsum,
                                               float* __restrict__ nout) {
    __shared__ float sA[32][72];
    __shared__ float sB[32][128];
    int t = threadIdx.x;
    int n0 = blockIdx.x * 64;
    int g = t & 31;
    int ng = t >> 5;

    float acc[8][4];
    #pragma unroll
    for (int j = 0; j < 8; j++)
        #pragma unroll
        for (int q = 0; q < 4; q++) acc[j][q] = 0.f;

    int ldn = t >> 2;
    int ldk = (t & 3) * 8;
    int an = n0 + ldn; if (an >= NN) an = NN - 1;
    const float* Arow = A + (size_t)an * 512;
    int bk = t >> 3;
    int bo = (t & 7) * 16;

    for (int kc = 0; kc < 512; kc += 32) {
        __syncthreads();
        float4 a0 = *(const float4*)(Arow + kc + ldk);
        float4 a1 = *(const float4*)(Arow + kc + ldk + 4);
        sA[ldk + 0][ldn] = a0.x; sA[ldk + 1][ldn] = a0.y;
        sA[ldk + 2][ldn] = a0.z; sA[ldk + 3][ldn] = a0.w;
        sA[ldk + 4][ldn] = a1.x; sA[ldk + 5][ldn] = a1.y;
        sA[ldk + 6][ldn] = a1.z; sA[ldk + 7][ldn] = a1.w;
        const float* bp = Wcomb + (size_t)(kc + bk) * 128 + bo;
        float4 b0 = *(const float4*)(bp);
        float4 b1 = *(const float4*)(bp + 4);
        float4 b2 = *(const float4*)(bp + 8);
        float4 b3 = *(const float4*)(bp + 12);
        *(float4*)&sB[bk][bo]      = b0;
        *(float4*)&sB[bk][bo + 4]  = b1;
        *(float4*)&sB[bk][bo + 8]  = b2;
        *(float4*)&sB[bk][bo + 12] = b3;
        __syncthreads();
        #pragma unroll 8
        for (int k = 0; k < 32; k++) {
            float4 b = *(const float4*)&sB[k][g * 4];
            float4 x0 = *(const float4*)&sA[k][ng * 8];
            float4 x1 = *(const float4*)&sA[k][ng * 8 + 4];
            float av[8] = {x0.x, x0.y, x0.z, x0.w, x1.x, x1.y, x1.z, x1.w};
            #pragma unroll
            for (int j = 0; j < 8; j++) {
                acc[j][0] += av[j] * b.x;
                acc[j][1] += av[j] * b.y;
                acc[j][2] += av[j] * b.z;
                acc[j][3] += av[j] * b.w;
            }
        }
    }

    float avg_log = *avgsum / (float)NN;
    float4 bv = *(const float4*)(bno + (g & 15) * 4);
    #pragma unroll
    for (int j = 0; j < 8; j++) {
        int n = n0 + ng * 8 + j;
        float p0 = __shfl_xor(acc[j][0], 16);
        float p1 = __shfl_xor(acc[j][1], 16);
        float p2 = __shfl_xor(acc[j][2], 16);
        float p3 = __shfl_xor(acc[j][3], 16);
        if (g < 16 && n < NN) {
            float cnt = (float)counts[n];
            float ld = logf(fmaxf(cnt, 1.0f) + 1.0f);
            float s1 = ld / avg_log;
            float4 o;
            o.x = acc[j][0] + s1 * p0 + bv.x;
            o.y = acc[j][1] + s1 * p1 + bv.y;
            o.z = acc[j][2] + s1 * p2 + bv.z;
            o.w = acc[j][3] + s1 * p3 + bv.w;
            *(float4*)(nout + (size_t)n * 64 + g * 4) = o;
        }
    }
}

extern "C" void kernel_launch(void* const* d_in, const int* in_sizes, int n_in,
                              void* d_out, int out_size, void* d_ws, size_t ws_size,
                              hipStream_t stream) {
    const float* x         = (const float*)d_in[0];
    const float* edge_attr = (const float*)d_in[1];
    const int*   ei        = (const int*)d_in[2];
    const float* W_l       = (const float*)d_in[3];
    const float* b_l       = (const float*)d_in[4];
    const float* W_e       = (const float*)d_in[5];
    const float* b_e       = (const float*)d_in[6];
    const float* att       = (const float*)d_in[7];
    const float* W_no      = (const float*)d_in[8];
    const float* b_no      = (const float*)d_in[9];
    const float* W_eo      = (const float*)d_in[10];
    const float* b_eo      = (const float*)d_in[11];

    float* nout = (float*)d_out;                    // [N, 64]
    float* eout = (float*)d_out + (size_t)NN * 64;  // [E, 32]

    char* ws = (char*)d_ws;
    size_t off = 0;
    auto take = [&](size_t bytes) -> char* {
        char* p = ws + off;
        off = (off + bytes + 255) & ~(size_t)255;
        return p;
    };
    float* xl        = (float*)take((size_t)NN * 128 * 4);
    float* ai        = (float*)take((size_t)NN * 2 * 4);
    float* aj        = (float*)take((size_t)NN * 2 * 4);
    float* csr_logit = (float*)take((size_t)EE * 2 * 4);
    int*   csr_src   = (int*)take((size_t)EE * 4);
    int*   counts    = (int*)take((size_t)NN * 4);
    int*   offsets   = (int*)take((size_t)NN * 4);
    int*   fill      = (int*)take((size_t)NN * 4);
    int*   bsums     = (int*)take(256 * 4);
    float* Wc        = (float*)take(32 * 32 * 4);
    float* bc        = (float*)take(32 * 4);
    float* Wcomb     = (float*)take(512 * 128 * 4);
    float* avgsum    = (float*)take(4);
    float* out_ws    = (float*)take((size_t)NN * 512 * 4);

    hipMemsetAsync(counts, 0, (size_t)NN * 4, stream);
    hipMemsetAsync(fill, 0, (size_t)NN * 4, stream);
    hipMemsetAsync(avgsum, 0, 4, stream);

    k_combine<<<1, 1024, 0, stream>>>(W_e, b_e, W_eo, b_eo, Wc, bc);
    k_prepw<<<512, 128, 0, stream>>>(W_no, Wcomb);
    k_node2<<<(NN + 63) / 64, 256, 0, stream>>>(x, W_l, b_l, att, xl, ai, aj);
    k_count<<<(EE + 255) / 256, 256, 0, stream>>>(ei, counts);
    int nb = (NN + 1023) / 1024;
    k_scan1<<<nb, 1024, 0, stream>>>(counts, offsets, bsums, avgsum);
    k_scan2<<<1, 64, 0, stream>>>(bsums, nb);
    k_scan3<<<nb, 1024, 0, stream>>>(offsets, bsums);
    k_edge3<<<EE / 256, 256, 0, stream>>>(edge_attr, ei, W_e, b_e, att, Wc, bc,
                                          ai, aj, offsets, fill,
                                          csr_src, csr_logit, eout);
    k_aggr<<<(NN + 3) / 4, 256, 0, stream>>>(counts, offsets, csr_src, csr_logit,
                                             xl, out_ws);
    k_proj2<<<(NN + 63) / 64, 256, 0, stream>>>(out_ws, Wcomb, b_no, counts, avgsum, nout);
}

// Round 7
// 394.492 us; speedup vs baseline: 2.5388x; 1.0922x over previous
//
#include <hip/hip_runtime.h>
#include <hip/hip_bf16.h>

#define NN 50000
#define EE 800000
#define HH 2
#define CC 64
#define CEE 32

typedef __attribute__((ext_vector_type(8))) short bf16x8;
typedef __attribute__((ext_vector_type(4))) float f32x4;

__device__ __forceinline__ short f2bf(float f) {
    union { float f; unsigned u; } v; v.f = f;
    unsigned r = v.u + 0x7FFF + ((v.u >> 16) & 1);   // RNE
    return (short)(r >> 16);
}

// ---------------- K0: combined edge weights: Wc = W_e @ W_eo, bc = b_e @ W_eo + b_eo
__global__ void k_combine(const float* __restrict__ We, const float* __restrict__ be,
                          const float* __restrict__ Weo, const float* __restrict__ beo,
                          float* __restrict__ Wc, float* __restrict__ bc) {
    int t = threadIdx.x;
    int i = t >> 5, j = t & 31;           // 32 x 32
    float s = 0.f;
    #pragma unroll
    for (int k = 0; k < 64; k++) s += We[i * 64 + k] * Weo[k * 32 + j];
    Wc[i * 32 + j] = s;
    if (t < 32) {
        float b = beo[t];
        #pragma unroll
        for (int k = 0; k < 64; k++) b += be[k] * Weo[k * 32 + t];
        bc[t] = b;
    }
}

// ---------------- K0b: projection weights combined: Wcomb[512][128]
__global__ void k_prepw(const float* __restrict__ Wno, float* __restrict__ Wcomb) {
    int r = blockIdx.x;        // 0..511  (= h*256 + agg*64 + c)
    int o = threadIdx.x;       // 0..127
    int h = r >> 8, q = r & 255;
    const float* base = Wno + (size_t)(h * 768 + q) * 64;
    float v;
    if (o < 64) v = base[o] + base[512 * 64 + o];
    else        v = base[256 * 64 + (o - 64)];
    Wcomb[r * 128 + o] = v;
}

// ---------------- K1: tiled GEMM xl = x @ W_l + b_l, fused ai/aj epilogue
__global__ __launch_bounds__(256) void k_node2(const float* __restrict__ x,
                                               const float* __restrict__ Wl,
                                               const float* __restrict__ bl,
                                               const float* __restrict__ att,
                                               float* __restrict__ xl,
                                               float* __restrict__ ai,
                                               float* __restrict__ aj) {
    __shared__ float sX[32][72];     // k-major x tile (64 nodes)
    __shared__ float sW[32][128];
    int t = threadIdx.x;
    int n0 = blockIdx.x * 64;
    int g = t & 31;                  // output col group: 4g..4g+3
    int ng = t >> 5;                 // node subgroup (8 nodes each)

    float acc[8][4];
    #pragma unroll
    for (int j = 0; j < 8; j++)
        #pragma unroll
        for (int q = 0; q < 4; q++) acc[j][q] = 0.f;

    int ldn = t >> 2;                // 0..63
    int ldk = (t & 3) * 8;           // 0,8,16,24
    int an = n0 + ldn; if (an >= NN) an = NN - 1;
    const float* Arow = x + (size_t)an * 128;
    int bk = t >> 3;                 // 0..31
    int bo = (t & 7) * 16;           // 0..112

    for (int kc = 0; kc < 128; kc += 32) {
        __syncthreads();
        float4 a0 = *(const float4*)(Arow + kc + ldk);
        float4 a1 = *(const float4*)(Arow + kc + ldk + 4);
        sX[ldk + 0][ldn] = a0.x; sX[ldk + 1][ldn] = a0.y;
        sX[ldk + 2][ldn] = a0.z; sX[ldk + 3][ldn] = a0.w;
        sX[ldk + 4][ldn] = a1.x; sX[ldk + 5][ldn] = a1.y;
        sX[ldk + 6][ldn] = a1.z; sX[ldk + 7][ldn] = a1.w;
        const float* bp = Wl + (size_t)(kc + bk) * 128 + bo;
        float4 b0 = *(const float4*)(bp);
        float4 b1 = *(const float4*)(bp + 4);
        float4 b2 = *(const float4*)(bp + 8);
        float4 b3 = *(const float4*)(bp + 12);
        *(float4*)&sW[bk][bo]      = b0;
        *(float4*)&sW[bk][bo + 4]  = b1;
        *(float4*)&sW[bk][bo + 8]  = b2;
        *(float4*)&sW[bk][bo + 12] = b3;
        __syncthreads();
        #pragma unroll 8
        for (int k = 0; k < 32; k++) {
            float4 b = *(const float4*)&sW[k][g * 4];
            float4 x0 = *(const float4*)&sX[k][ng * 8];
            float4 x1 = *(const float4*)&sX[k][ng * 8 + 4];
            float av[8] = {x0.x, x0.y, x0.z, x0.w, x1.x, x1.y, x1.z, x1.w};
            #pragma unroll
            for (int j = 0; j < 8; j++) {
                acc[j][0] += av[j] * b.x;
                acc[j][1] += av[j] * b.y;
                acc[j][2] += av[j] * b.z;
                acc[j][3] += av[j] * b.w;
            }
        }
    }

    float4 bv = *(const float4*)(bl + g * 4);
    int h = g >> 4;
    float atti[4], attj[4];
    #pragma unroll
    for (int q = 0; q < 4; q++) {
        int c = 4 * (g & 15) + q;
        atti[q] = att[h * 160 + c];
        attj[q] = att[h * 160 + 64 + c];
    }
    #pragma unroll
    for (int j = 0; j < 8; j++) {
        int n = n0 + ng * 8 + j;
        float v[4] = {acc[j][0] + bv.x, acc[j][1] + bv.y,
                      acc[j][2] + bv.z, acc[j][3] + bv.w};
        if (n < NN)
            *(float4*)(xl + (size_t)n * 128 + g * 4) = make_float4(v[0], v[1], v[2], v[3]);
        float sA = 0.f, sJ = 0.f;
        #pragma unroll
        for (int q = 0; q < 4; q++) {
            float lr = v[q] > 0.f ? v[q] : 0.2f * v[q];
            sA += lr * atti[q];
            sJ += lr * attj[q];
        }
        #pragma unroll
        for (int m = 1; m <= 8; m <<= 1) {
            sA += __shfl_xor(sA, m);
            sJ += __shfl_xor(sJ, m);
        }
        if ((g & 15) == 0 && n < NN) {
            ai[n * 2 + h] = sA;
            aj[n * 2 + h] = sJ;
        }
    }
}

// ---------------- K2a: degree counts over dst
__global__ void k_count(const int* __restrict__ ei, int* __restrict__ counts) {
    int e = blockIdx.x * 256 + threadIdx.x;
    if (e < EE) atomicAdd(&counts[ei[EE + e]], 1);
}

// ---------------- scan (3 kernels); k_scan1 also folds in avg_log accumulation
__global__ __launch_bounds__(1024) void k_scan1(const int* __restrict__ counts,
                                                int* __restrict__ offsets,
                                                int* __restrict__ bsums,
                                                float* __restrict__ avgsum) {
    __shared__ int s[1024];
    int g = blockIdx.x * 1024 + threadIdx.x;
    int v = (g < NN) ? counts[g] : 0;
    s[threadIdx.x] = v;
    __syncthreads();
    for (int st = 1; st < 1024; st <<= 1) {
        int t = (threadIdx.x >= st) ? s[threadIdx.x - st] : 0;
        __syncthreads();
        s[threadIdx.x] += t;
        __syncthreads();
    }
    if (g < NN) offsets[g] = s[threadIdx.x] - v;
    if (threadIdx.x == 1023) bsums[blockIdx.x] = s[1023];
    float lv = (g < NN) ? logf((float)v + 1.0f) : 0.0f;
    #pragma unroll
    for (int m = 32; m; m >>= 1) lv += __shfl_xor(lv, m);
    if ((threadIdx.x & 63) == 0) atomicAdd(avgsum, lv);
}

__global__ void k_scan2(int* __restrict__ bsums, int nb) {
    if (threadIdx.x == 0 && blockIdx.x == 0) {
        int c = 0;
        for (int i = 0; i < nb; i++) { int t = bsums[i]; bsums[i] = c; c += t; }
    }
}

__global__ __launch_bounds__(1024) void k_scan3(int* __restrict__ offsets,
                                                const int* __restrict__ bsums) {
    int g = blockIdx.x * 1024 + threadIdx.x;
    if (g < NN) offsets[g] += bsums[blockIdx.x];
}

// ---------------- K3: MFMA edge pass, MLP-optimized.
// Per wave: 64 edges. All ea loads + per-lane edge metadata hoisted upfront.
// After the 2-shuffle reduce in group g, lane L holds the logit sums of edge
// g*16+(L&15); lanes with (L>>4)==g keep them, so the CSR scatter runs once
// with all 64 lanes active, as a single packed 16B store per edge.
__global__ __launch_bounds__(256) void k_edge4(const float* __restrict__ ea,
                                               const int* __restrict__ ei,
                                               const float* __restrict__ We,
                                               const float* __restrict__ be,
                                               const float* __restrict__ att,
                                               const float* __restrict__ Wc,
                                               const float* __restrict__ bc,
                                               const float* __restrict__ ai,
                                               const float* __restrict__ aj,
                                               const int* __restrict__ offsets,
                                               int* __restrict__ fill,
                                               float4* __restrict__ csr4,
                                               float* __restrict__ eout) {
    int t = threadIdx.x;
    int lane = t & 63, wave = t >> 6;
    int l15 = lane & 15, lq = lane >> 4;
    int ew0 = blockIdx.x * 256 + wave * 64;

    // ---- hoisted loads: 8 float4 of edge attrs + own-edge metadata
    float4 f[4][2];
    #pragma unroll
    for (int g = 0; g < 4; g++) {
        const float4* p = (const float4*)(ea + (size_t)(ew0 + g * 16 + l15) * 32 + lq * 8);
        f[g][0] = p[0];
        f[g][1] = p[1];
    }
    int myE = ew0 + lane;
    int msrc = ei[myE], mdst = ei[EE + myE];
    float2 aiv = *(const float2*)(ai + (size_t)mdst * 2);
    float2 ajv = *(const float2*)(aj + (size_t)msrc * 2);

    // ---- register weights (A-frags) + bias/att rows
    bf16x8 aWe[4], aWc[2];
    #pragma unroll
    for (int mb = 0; mb < 4; mb++)
        #pragma unroll
        for (int j = 0; j < 8; j++)
            aWe[mb][j] = f2bf(We[(lq * 8 + j) * 64 + mb * 16 + l15]);
    #pragma unroll
    for (int cb = 0; cb < 2; cb++)
        #pragma unroll
        for (int j = 0; j < 8; j++)
            aWc[cb][j] = f2bf(Wc[(lq * 8 + j) * 32 + cb * 16 + l15]);

    f32x4 beC[4], bcC[2];
    float attR[4][4];
    #pragma unroll
    for (int mb = 0; mb < 4; mb++)
        #pragma unroll
        for (int r = 0; r < 4; r++) {
            int m = mb * 16 + lq * 4 + r;
            beC[mb][r] = be[m];
            attR[mb][r] = att[(m >> 5) * 160 + 128 + (m & 31)];
        }
    #pragma unroll
    for (int cb = 0; cb < 2; cb++)
        #pragma unroll
        for (int r = 0; r < 4; r++)
            bcC[cb][r] = bc[cb * 16 + lq * 4 + r];

    float myP0 = 0.f, myP1 = 0.f;

    #pragma unroll
    for (int g = 0; g < 4; g++) {
        int e = ew0 + g * 16 + l15;
        float4 f0 = f[g][0], f1 = f[g][1];
        bf16x8 bE;
        bE[0] = f2bf(f0.x); bE[1] = f2bf(f0.y); bE[2] = f2bf(f0.z); bE[3] = f2bf(f0.w);
        bE[4] = f2bf(f1.x); bE[5] = f2bf(f1.y); bE[6] = f2bf(f1.z); bE[7] = f2bf(f1.w);

        // logits: m = lrelu(ea@We + be); per-head att dot
        float p0 = 0.f, p1 = 0.f;
        #pragma unroll
        for (int mb = 0; mb < 4; mb++) {
            f32x4 acc = __builtin_amdgcn_mfma_f32_16x16x32_bf16(aWe[mb], bE, beC[mb], 0, 0, 0);
            float ps = 0.f;
            #pragma unroll
            for (int r = 0; r < 4; r++) {
                float m = acc[r];
                float lr = m > 0.f ? m : 0.2f * m;
                ps += lr * attR[mb][r];
            }
            if (mb < 2) p0 += ps; else p1 += ps;
        }
        p0 += __shfl_xor(p0, 16); p0 += __shfl_xor(p0, 32);
        p1 += __shfl_xor(p1, 16); p1 += __shfl_xor(p1, 32);
        if (lq == g) { myP0 = p0; myP1 = p1; }

        // eout = ea@Wc + bc (coalesced 2KB per wave-group)
        #pragma unroll
        for (int cb = 0; cb < 2; cb++) {
            f32x4 oc = __builtin_amdgcn_mfma_f32_16x16x32_bf16(aWc[cb], bE, bcC[cb], 0, 0, 0);
            *(float4*)(eout + (size_t)e * 32 + cb * 16 + lq * 4) =
                make_float4(oc[0], oc[1], oc[2], oc[3]);
        }
    }

    // ---- CSR scatter: all 64 lanes, one packed 16B store per edge
    float lg0 = myP0 + aiv.x + ajv.x;
    float lg1 = myP1 + aiv.y + ajv.y;
    int pos = offsets[mdst] + atomicAdd(&fill[mdst], 1);
    csr4[pos] = make_float4(__int_as_float(msrc), lg0, lg1, 0.f);
}

// ---------------- K4: one wave per NODE, both heads fused (packed CSR reads)
__global__ __launch_bounds__(256) void k_aggr(const int* __restrict__ counts,
                                              const int* __restrict__ offsets,
                                              const float4* __restrict__ csr4,
                                              const float* __restrict__ xl,
                                              float* __restrict__ out_ws) {
    int lane = threadIdx.x & 63;
    int wv = threadIdx.x >> 6;
    int n = blockIdx.x * 4 + wv;
    if (n >= NN) return;
    int deg = counts[n], start = offsets[n];

    float sum0 = 0.f, sum1 = 0.f, sq0 = 0.f, sq1 = 0.f;
    float mn0 = 1e30f, mn1 = 1e30f, mx0 = -1e30f, mx1 = -1e30f;

    if (deg > 0 && deg <= 64) {
        float2 lg = make_float2(-1e30f, -1e30f);
        int srcv = 0;
        if (lane < deg) {
            float4 c = csr4[start + lane];
            srcv = __float_as_int(c.x);
            lg = make_float2(c.y, c.z);
        }
        float m0 = lg.x, m1 = lg.y;
        #pragma unroll
        for (int s = 32; s; s >>= 1) {
            m0 = fmaxf(m0, __shfl_xor(m0, s));
            m1 = fmaxf(m1, __shfl_xor(m1, s));
        }
        float e0 = (lane < deg) ? __expf(lg.x - m0) : 0.f;
        float e1 = (lane < deg) ? __expf(lg.y - m1) : 0.f;
        float s0 = e0, s1 = e1;
        #pragma unroll
        for (int s = 32; s; s >>= 1) {
            s0 += __shfl_xor(s0, s);
            s1 += __shfl_xor(s1, s);
        }
        float a0 = e0 / (s0 + 1e-16f);
        float a1 = e1 / (s1 + 1e-16f);

        for (int i = 0; i < deg; i++) {
            int sidx = __shfl(srcv, i);
            float al0 = __shfl(a0, i);
            float al1 = __shfl(a1, i);
            float alpha = (lane < 32) ? al0 : al1;
            float2 v = *(const float2*)(xl + (size_t)sidx * 128 + lane * 2);
            float g0 = v.x * alpha, g1 = v.y * alpha;
            sum0 += g0; sum1 += g1;
            sq0 += g0 * g0; sq1 += g1 * g1;
            mn0 = fminf(mn0, g0); mn1 = fminf(mn1, g1);
            mx0 = fmaxf(mx0, g0); mx1 = fmaxf(mx1, g1);
        }
    } else if (deg > 64) {
        float m0 = -1e30f, m1 = -1e30f;
        for (int i = lane; i < deg; i += 64) {
            float4 c = csr4[start + i];
            m0 = fmaxf(m0, c.y); m1 = fmaxf(m1, c.z);
        }
        #pragma unroll
        for (int s = 32; s; s >>= 1) {
            m0 = fmaxf(m0, __shfl_xor(m0, s));
            m1 = fmaxf(m1, __shfl_xor(m1, s));
        }
        float s0 = 0.f, s1 = 0.f;
        for (int i = lane; i < deg; i += 64) {
            float4 c = csr4[start + i];
            s0 += __expf(c.y - m0); s1 += __expf(c.z - m1);
        }
        #pragma unroll
        for (int s = 32; s; s >>= 1) {
            s0 += __shfl_xor(s0, s);
            s1 += __shfl_xor(s1, s);
        }
        float inv0 = 1.0f / (s0 + 1e-16f), inv1 = 1.0f / (s1 + 1e-16f);
        for (int i = 0; i < deg; i++) {
            float4 c = csr4[start + i];
            int sidx = __float_as_int(c.x);
            float al0 = __expf(c.y - m0) * inv0;
            float al1 = __expf(c.z - m1) * inv1;
            float alpha = (lane < 32) ? al0 : al1;
            float2 v = *(const float2*)(xl + (size_t)sidx * 128 + lane * 2);
            float g0 = v.x * alpha, g1 = v.y * alpha;
            sum0 += g0; sum1 += g1;
            sq0 += g0 * g0; sq1 += g1 * g1;
            mn0 = fminf(mn0, g0); mn1 = fminf(mn1, g1);
            mx0 = fmaxf(mx0, g0); mx1 = fmaxf(mx1, g1);
        }
    } else {
        mn0 = mn1 = mx0 = mx1 = 0.f;
    }

    float cc = deg > 0 ? (float)deg : 1.0f;
    float mean0 = sum0 / cc, mean1 = sum1 / cc;
    float sd0 = sqrtf(fmaxf(sq0 / cc - mean0 * mean0, 0.0f) + 1e-5f);
    float sd1 = sqrtf(fmaxf(sq1 / cc - mean1 * mean1, 0.0f) + 1e-5f);

    int c2 = lane * 2, h = c2 >> 6, c = c2 & 63;
    float* ob = out_ws + (size_t)n * 512 + h * 256 + c;
    *(float2*)(ob + 0)   = make_float2(mean0, mean1);
    *(float2*)(ob + 64)  = make_float2(mn0, mn1);
    *(float2*)(ob + 128) = make_float2(mx0, mx1);
    *(float2*)(ob + 192) = make_float2(sd0, sd1);
}

// ---------------- K5: tiled fp32 GEMM  out = A[N,512] @ Wcomb[512,128]
__global__ __launch_bounds__(256) void k_proj2(const float* __restrict__ A,
                                               const float* __restrict__ Wcomb,
                                               const float* __restrict__ bno,
                                               const int* __restrict__ counts,
                                               const float* __restrict__ avgsum,
                                               float* __restrict__ nout) {
    __shared__ float sA[32][72];
    __shared__ float sB[32][128];
    int t = threadIdx.x;
    int n0 = blockIdx.x * 64;
    int g = t & 31;
    int ng = t >> 5;

    float acc[8][4];
    #pragma unroll
    for (int j = 0; j < 8; j++)
        #pragma unroll
        for (int q = 0; q < 4; q++) acc[j][q] = 0.f;

    int ldn = t >> 2;
    int ldk = (t & 3) * 8;
    int an = n0 + ldn; if (an >= NN) an = NN - 1;
    const float* Arow = A + (size_t)an * 512;
    int bk = t >> 3;
    int bo = (t & 7) * 16;

    for (int kc = 0; kc < 512; kc += 32) {
        __syncthreads();
        float4 a0 = *(const float4*)(Arow + kc + ldk);
        float4 a1 = *(const float4*)(Arow + kc + ldk + 4);
        sA[ldk + 0][ldn] = a0.x; sA[ldk + 1][ldn] = a0.y;
        sA[ldk + 2][ldn] = a0.z; sA[ldk + 3][ldn] = a0.w;
        sA[ldk + 4][ldn] = a1.x; sA[ldk + 5][ldn] = a1.y;
        sA[ldk + 6][ldn] = a1.z; sA[ldk + 7][ldn] = a1.w;
        const float* bp = Wcomb + (size_t)(kc + bk) * 128 + bo;
        float4 b0 = *(const float4*)(bp);
        float4 b1 = *(const float4*)(bp + 4);
        float4 b2 = *(const float4*)(bp + 8);
        float4 b3 = *(const float4*)(bp + 12);
        *(float4*)&sB[bk][bo]      = b0;
        *(float4*)&sB[bk][bo + 4]  = b1;
        *(float4*)&sB[bk][bo + 8]  = b2;
        *(float4*)&sB[bk][bo + 12] = b3;
        __syncthreads();
        #pragma unroll 8
        for (int k = 0; k < 32; k++) {
            float4 b = *(const float4*)&sB[k][g * 4];
            float4 x0 = *(const float4*)&sA[k][ng * 8];
            float4 x1 = *(const float4*)&sA[k][ng * 8 + 4];
            float av[8] = {x0.x, x0.y, x0.z, x0.w, x1.x, x1.y, x1.z, x1.w};
            #pragma unroll
            for (int j = 0; j < 8; j++) {
                acc[j][0] += av[j] * b.x;
                acc[j][1] += av[j] * b.y;
                acc[j][2] += av[j] * b.z;
                acc[j][3] += av[j] * b.w;
            }
        }
    }

    float avg_log = *avgsum / (float)NN;
    float4 bv = *(const float4*)(bno + (g & 15) * 4);
    #pragma unroll
    for (int j = 0; j < 8; j++) {
        int n = n0 + ng * 8 + j;
        float p0 = __shfl_xor(acc[j][0], 16);
        float p1 = __shfl_xor(acc[j][1], 16);
        float p2 = __shfl_xor(acc[j][2], 16);
        float p3 = __shfl_xor(acc[j][3], 16);
        if (g < 16 && n < NN) {
            float cnt = (float)counts[n];
            float ld = logf(fmaxf(cnt, 1.0f) + 1.0f);
            float s1 = ld / avg_log;
            float4 o;
            o.x = acc[j][0] + s1 * p0 + bv.x;
            o.y = acc[j][1] + s1 * p1 + bv.y;
            o.z = acc[j][2] + s1 * p2 + bv.z;
            o.w = acc[j][3] + s1 * p3 + bv.w;
            *(float4*)(nout + (size_t)n * 64 + g * 4) = o;
        }
    }
}

extern "C" void kernel_launch(void* const* d_in, const int* in_sizes, int n_in,
                              void* d_out, int out_size, void* d_ws, size_t ws_size,
                              hipStream_t stream) {
    const float* x         = (const float*)d_in[0];
    const float* edge_attr = (const float*)d_in[1];
    const int*   ei        = (const int*)d_in[2];
    const float* W_l       = (const float*)d_in[3];
    const float* b_l       = (const float*)d_in[4];
    const float* W_e       = (const float*)d_in[5];
    const float* b_e       = (const float*)d_in[6];
    const float* att       = (const float*)d_in[7];
    const float* W_no      = (const float*)d_in[8];
    const float* b_no      = (const float*)d_in[9];
    const float* W_eo      = (const float*)d_in[10];
    const float* b_eo      = (const float*)d_in[11];

    float* nout = (float*)d_out;                    // [N, 64]
    float* eout = (float*)d_out + (size_t)NN * 64;  // [E, 32]

    char* ws = (char*)d_ws;
    size_t off = 0;
    auto take = [&](size_t bytes) -> char* {
        char* p = ws + off;
        off = (off + bytes + 255) & ~(size_t)255;
        return p;
    };
    float* xl        = (float*)take((size_t)NN * 128 * 4);
    float* ai        = (float*)take((size_t)NN * 2 * 4);
    float* aj        = (float*)take((size_t)NN * 2 * 4);
    float4* csr4     = (float4*)take((size_t)EE * 16);
    int*   counts    = (int*)take((size_t)NN * 4);
    int*   offsets   = (int*)take((size_t)NN * 4);
    int*   fill      = (int*)take((size_t)NN * 4);
    int*   bsums     = (int*)take(256 * 4);
    float* Wc        = (float*)take(32 * 32 * 4);
    float* bc        = (float*)take(32 * 4);
    float* Wcomb     = (float*)take(512 * 128 * 4);
    float* avgsum    = (float*)take(4);
    float* out_ws    = (float*)take((size_t)NN * 512 * 4);

    hipMemsetAsync(counts, 0, (size_t)NN * 4, stream);
    hipMemsetAsync(fill, 0, (size_t)NN * 4, stream);
    hipMemsetAsync(avgsum, 0, 4, stream);

    k_combine<<<1, 1024, 0, stream>>>(W_e, b_e, W_eo, b_eo, Wc, bc);
    k_prepw<<<512, 128, 0, stream>>>(W_no, Wcomb);
    k_node2<<<(NN + 63) / 64, 256, 0, stream>>>(x, W_l, b_l, att, xl, ai, aj);
    k_count<<<(EE + 255) / 256, 256, 0, stream>>>(ei, counts);
    int nb = (NN + 1023) / 1024;
    k_scan1<<<nb, 1024, 0, stream>>>(counts, offsets, bsums, avgsum);
    k_scan2<<<1, 64, 0, stream>>>(bsums, nb);
    k_scan3<<<nb, 1024, 0, stream>>>(offsets, bsums);
    k_edge4<<<EE / 256, 256, 0, stream>>>(edge_attr, ei, W_e, b_e, att, Wc, bc,
                                          ai, aj, offsets, fill, csr4, eout);
    k_aggr<<<(NN + 3) / 4, 256, 0, stream>>>(counts, offsets, csr4, xl, out_ws);
    k_proj2<<<(NN + 63) / 64, 256, 0, stream>>>(out_ws, Wcomb, b_no, counts, avgsum, nout);
}

// Round 8
// 303.160 us; speedup vs baseline: 3.3037x; 1.3013x over previous
//
#include <hip/hip_runtime.h>
#include <hip/hip_bf16.h>

#define NN 50000
#define EE 800000
#define HH 2
#define CC 64
#define CEE 32

typedef __attribute__((ext_vector_type(8))) short bf16x8;
typedef __attribute__((ext_vector_type(4))) float f32x4;

__device__ __forceinline__ short f2bf(float f) {
    union { float f; unsigned u; } v; v.f = f;
    unsigned r = v.u + 0x7FFF + ((v.u >> 16) & 1);   // RNE
    return (short)(r >> 16);
}
__device__ __forceinline__ unsigned pack2(float a, float b) {
    return (unsigned)(unsigned short)f2bf(a) | ((unsigned)(unsigned short)f2bf(b) << 16);
}

// ---------------- K0: combined edge weights: Wc = W_e @ W_eo, bc = b_e @ W_eo + b_eo
__global__ void k_combine(const float* __restrict__ We, const float* __restrict__ be,
                          const float* __restrict__ Weo, const float* __restrict__ beo,
                          float* __restrict__ Wc, float* __restrict__ bc) {
    int t = threadIdx.x;
    int i = t >> 5, j = t & 31;           // 32 x 32
    float s = 0.f;
    #pragma unroll
    for (int k = 0; k < 64; k++) s += We[i * 64 + k] * Weo[k * 32 + j];
    Wc[i * 32 + j] = s;
    if (t < 32) {
        float b = beo[t];
        #pragma unroll
        for (int k = 0; k < 64; k++) b += be[k] * Weo[k * 32 + t];
        bc[t] = b;
    }
}

// ---------------- K0b: projection weights, transposed bf16: WT[128 cols][512 r]
// col o<64 : W1+W3 ; col o>=64 : W2 (amplify)
__global__ __launch_bounds__(512) void k_prepw2(const float* __restrict__ Wno,
                                                unsigned short* __restrict__ WT) {
    int o = blockIdx.x;        // 0..127
    int r = threadIdx.x;       // 0..511  (= h*256 + agg*64 + c)
    int h = r >> 8, q = r & 255;
    const float* base = Wno + (size_t)(h * 768 + q) * 64;
    float v;
    if (o < 64) v = base[o] + base[512 * 64 + o];
    else        v = base[256 * 64 + (o - 64)];
    WT[(size_t)o * 512 + r] = (unsigned short)f2bf(v);
}

// ---------------- K1: tiled GEMM xl = x @ W_l + b_l, fused ai/aj epilogue
__global__ __launch_bounds__(256) void k_node2(const float* __restrict__ x,
                                               const float* __restrict__ Wl,
                                               const float* __restrict__ bl,
                                               const float* __restrict__ att,
                                               float* __restrict__ xl,
                                               float* __restrict__ ai,
                                               float* __restrict__ aj) {
    __shared__ float sX[32][72];     // k-major x tile (64 nodes)
    __shared__ float sW[32][128];
    int t = threadIdx.x;
    int n0 = blockIdx.x * 64;
    int g = t & 31;                  // output col group: 4g..4g+3
    int ng = t >> 5;                 // node subgroup (8 nodes each)

    float acc[8][4];
    #pragma unroll
    for (int j = 0; j < 8; j++)
        #pragma unroll
        for (int q = 0; q < 4; q++) acc[j][q] = 0.f;

    int ldn = t >> 2;                // 0..63
    int ldk = (t & 3) * 8;           // 0,8,16,24
    int an = n0 + ldn; if (an >= NN) an = NN - 1;
    const float* Arow = x + (size_t)an * 128;
    int bk = t >> 3;                 // 0..31
    int bo = (t & 7) * 16;           // 0..112

    for (int kc = 0; kc < 128; kc += 32) {
        __syncthreads();
        float4 a0 = *(const float4*)(Arow + kc + ldk);
        float4 a1 = *(const float4*)(Arow + kc + ldk + 4);
        sX[ldk + 0][ldn] = a0.x; sX[ldk + 1][ldn] = a0.y;
        sX[ldk + 2][ldn] = a0.z; sX[ldk + 3][ldn] = a0.w;
        sX[ldk + 4][ldn] = a1.x; sX[ldk + 5][ldn] = a1.y;
        sX[ldk + 6][ldn] = a1.z; sX[ldk + 7][ldn] = a1.w;
        const float* bp = Wl + (size_t)(kc + bk) * 128 + bo;
        float4 b0 = *(const float4*)(bp);
        float4 b1 = *(const float4*)(bp + 4);
        float4 b2 = *(const float4*)(bp + 8);
        float4 b3 = *(const float4*)(bp + 12);
        *(float4*)&sW[bk][bo]      = b0;
        *(float4*)&sW[bk][bo + 4]  = b1;
        *(float4*)&sW[bk][bo + 8]  = b2;
        *(float4*)&sW[bk][bo + 12] = b3;
        __syncthreads();
        #pragma unroll 8
        for (int k = 0; k < 32; k++) {
            float4 b = *(const float4*)&sW[k][g * 4];
            float4 x0 = *(const float4*)&sX[k][ng * 8];
            float4 x1 = *(const float4*)&sX[k][ng * 8 + 4];
            float av[8] = {x0.x, x0.y, x0.z, x0.w, x1.x, x1.y, x1.z, x1.w};
            #pragma unroll
            for (int j = 0; j < 8; j++) {
                acc[j][0] += av[j] * b.x;
                acc[j][1] += av[j] * b.y;
                acc[j][2] += av[j] * b.z;
                acc[j][3] += av[j] * b.w;
            }
        }
    }

    float4 bv = *(const float4*)(bl + g * 4);
    int h = g >> 4;
    float atti[4], attj[4];
    #pragma unroll
    for (int q = 0; q < 4; q++) {
        int c = 4 * (g & 15) + q;
        atti[q] = att[h * 160 + c];
        attj[q] = att[h * 160 + 64 + c];
    }
    #pragma unroll
    for (int j = 0; j < 8; j++) {
        int n = n0 + ng * 8 + j;
        float v[4] = {acc[j][0] + bv.x, acc[j][1] + bv.y,
                      acc[j][2] + bv.z, acc[j][3] + bv.w};
        if (n < NN)
            *(float4*)(xl + (size_t)n * 128 + g * 4) = make_float4(v[0], v[1], v[2], v[3]);
        float sA = 0.f, sJ = 0.f;
        #pragma unroll
        for (int q = 0; q < 4; q++) {
            float lr = v[q] > 0.f ? v[q] : 0.2f * v[q];
            sA += lr * atti[q];
            sJ += lr * attj[q];
        }
        #pragma unroll
        for (int m = 1; m <= 8; m <<= 1) {
            sA += __shfl_xor(sA, m);
            sJ += __shfl_xor(sJ, m);
        }
        if ((g & 15) == 0 && n < NN) {
            ai[n * 2 + h] = sA;
            aj[n * 2 + h] = sJ;
        }
    }
}

// ---------------- K2a: degree counts over dst
__global__ void k_count(const int* __restrict__ ei, int* __restrict__ counts) {
    int e = blockIdx.x * 256 + threadIdx.x;
    if (e < EE) atomicAdd(&counts[ei[EE + e]], 1);
}

// ---------------- scan (3 kernels); k_scan1 also folds in avg_log accumulation
__global__ __launch_bounds__(1024) void k_scan1(const int* __restrict__ counts,
                                                int* __restrict__ offsets,
                                                int* __restrict__ bsums,
                                                float* __restrict__ avgsum) {
    __shared__ int s[1024];
    int g = blockIdx.x * 1024 + threadIdx.x;
    int v = (g < NN) ? counts[g] : 0;
    s[threadIdx.x] = v;
    __syncthreads();
    for (int st = 1; st < 1024; st <<= 1) {
        int t = (threadIdx.x >= st) ? s[threadIdx.x - st] : 0;
        __syncthreads();
        s[threadIdx.x] += t;
        __syncthreads();
    }
    if (g < NN) offsets[g] = s[threadIdx.x] - v;
    if (threadIdx.x == 1023) bsums[blockIdx.x] = s[1023];
    float lv = (g < NN) ? logf((float)v + 1.0f) : 0.0f;
    #pragma unroll
    for (int m = 32; m; m >>= 1) lv += __shfl_xor(lv, m);
    if ((threadIdx.x & 63) == 0) atomicAdd(avgsum, lv);
}

__global__ void k_scan2(int* __restrict__ bsums, int nb) {
    if (threadIdx.x == 0 && blockIdx.x == 0) {
        int c = 0;
        for (int i = 0; i < nb; i++) { int t = bsums[i]; bsums[i] = c; c += t; }
    }
}

__global__ __launch_bounds__(1024) void k_scan3(int* __restrict__ offsets,
                                                const int* __restrict__ bsums) {
    int g = blockIdx.x * 1024 + threadIdx.x;
    if (g < NN) offsets[g] += bsums[blockIdx.x];
}

// ---------------- K3: MFMA edge pass (as round 7)
__global__ __launch_bounds__(256) void k_edge4(const float* __restrict__ ea,
                                               const int* __restrict__ ei,
                                               const float* __restrict__ We,
                                               const float* __restrict__ be,
                                               const float* __restrict__ att,
                                               const float* __restrict__ Wc,
                                               const float* __restrict__ bc,
                                               const float* __restrict__ ai,
                                               const float* __restrict__ aj,
                                               const int* __restrict__ offsets,
                                               int* __restrict__ fill,
                                               float4* __restrict__ csr4,
                                               float* __restrict__ eout) {
    int t = threadIdx.x;
    int lane = t & 63, wave = t >> 6;
    int l15 = lane & 15, lq = lane >> 4;
    int ew0 = blockIdx.x * 256 + wave * 64;

    float4 f[4][2];
    #pragma unroll
    for (int g = 0; g < 4; g++) {
        const float4* p = (const float4*)(ea + (size_t)(ew0 + g * 16 + l15) * 32 + lq * 8);
        f[g][0] = p[0];
        f[g][1] = p[1];
    }
    int myE = ew0 + lane;
    int msrc = ei[myE], mdst = ei[EE + myE];
    float2 aiv = *(const float2*)(ai + (size_t)mdst * 2);
    float2 ajv = *(const float2*)(aj + (size_t)msrc * 2);

    bf16x8 aWe[4], aWc[2];
    #pragma unroll
    for (int mb = 0; mb < 4; mb++)
        #pragma unroll
        for (int j = 0; j < 8; j++)
            aWe[mb][j] = f2bf(We[(lq * 8 + j) * 64 + mb * 16 + l15]);
    #pragma unroll
    for (int cb = 0; cb < 2; cb++)
        #pragma unroll
        for (int j = 0; j < 8; j++)
            aWc[cb][j] = f2bf(Wc[(lq * 8 + j) * 32 + cb * 16 + l15]);

    f32x4 beC[4], bcC[2];
    float attR[4][4];
    #pragma unroll
    for (int mb = 0; mb < 4; mb++)
        #pragma unroll
        for (int r = 0; r < 4; r++) {
            int m = mb * 16 + lq * 4 + r;
            beC[mb][r] = be[m];
            attR[mb][r] = att[(m >> 5) * 160 + 128 + (m & 31)];
        }
    #pragma unroll
    for (int cb = 0; cb < 2; cb++)
        #pragma unroll
        for (int r = 0; r < 4; r++)
            bcC[cb][r] = bc[cb * 16 + lq * 4 + r];

    float myP0 = 0.f, myP1 = 0.f;

    #pragma unroll
    for (int g = 0; g < 4; g++) {
        int e = ew0 + g * 16 + l15;
        float4 f0 = f[g][0], f1 = f[g][1];
        bf16x8 bE;
        bE[0] = f2bf(f0.x); bE[1] = f2bf(f0.y); bE[2] = f2bf(f0.z); bE[3] = f2bf(f0.w);
        bE[4] = f2bf(f1.x); bE[5] = f2bf(f1.y); bE[6] = f2bf(f1.z); bE[7] = f2bf(f1.w);

        float p0 = 0.f, p1 = 0.f;
        #pragma unroll
        for (int mb = 0; mb < 4; mb++) {
            f32x4 acc = __builtin_amdgcn_mfma_f32_16x16x32_bf16(aWe[mb], bE, beC[mb], 0, 0, 0);
            float ps = 0.f;
            #pragma unroll
            for (int r = 0; r < 4; r++) {
                float m = acc[r];
                float lr = m > 0.f ? m : 0.2f * m;
                ps += lr * attR[mb][r];
            }
            if (mb < 2) p0 += ps; else p1 += ps;
        }
        p0 += __shfl_xor(p0, 16); p0 += __shfl_xor(p0, 32);
        p1 += __shfl_xor(p1, 16); p1 += __shfl_xor(p1, 32);
        if (lq == g) { myP0 = p0; myP1 = p1; }

        #pragma unroll
        for (int cb = 0; cb < 2; cb++) {
            f32x4 oc = __builtin_amdgcn_mfma_f32_16x16x32_bf16(aWc[cb], bE, bcC[cb], 0, 0, 0);
            *(float4*)(eout + (size_t)e * 32 + cb * 16 + lq * 4) =
                make_float4(oc[0], oc[1], oc[2], oc[3]);
        }
    }

    float lg0 = myP0 + aiv.x + ajv.x;
    float lg1 = myP1 + aiv.y + ajv.y;
    int pos = offsets[mdst] + atomicAdd(&fill[mdst], 1);
    csr4[pos] = make_float4(__int_as_float(msrc), lg0, lg1, 0.f);
}

// ---------------- K4: one wave per NODE, both heads fused; bf16 out_ws
__global__ __launch_bounds__(256) void k_aggr(const int* __restrict__ counts,
                                              const int* __restrict__ offsets,
                                              const float4* __restrict__ csr4,
                                              const float* __restrict__ xl,
                                              unsigned short* __restrict__ out_ws) {
    int lane = threadIdx.x & 63;
    int wv = threadIdx.x >> 6;
    int n = blockIdx.x * 4 + wv;
    if (n >= NN) return;
    int deg = counts[n], start = offsets[n];

    float sum0 = 0.f, sum1 = 0.f, sq0 = 0.f, sq1 = 0.f;
    float mn0 = 1e30f, mn1 = 1e30f, mx0 = -1e30f, mx1 = -1e30f;

    if (deg > 0 && deg <= 64) {
        float2 lg = make_float2(-1e30f, -1e30f);
        int srcv = 0;
        if (lane < deg) {
            float4 c = csr4[start + lane];
            srcv = __float_as_int(c.x);
            lg = make_float2(c.y, c.z);
        }
        float m0 = lg.x, m1 = lg.y;
        #pragma unroll
        for (int s = 32; s; s >>= 1) {
            m0 = fmaxf(m0, __shfl_xor(m0, s));
            m1 = fmaxf(m1, __shfl_xor(m1, s));
        }
        float e0 = (lane < deg) ? __expf(lg.x - m0) : 0.f;
        float e1 = (lane < deg) ? __expf(lg.y - m1) : 0.f;
        float s0 = e0, s1 = e1;
        #pragma unroll
        for (int s = 32; s; s >>= 1) {
            s0 += __shfl_xor(s0, s);
            s1 += __shfl_xor(s1, s);
        }
        float a0 = e0 / (s0 + 1e-16f);
        float a1 = e1 / (s1 + 1e-16f);

        for (int i = 0; i < deg; i++) {
            int sidx = __shfl(srcv, i);
            float al0 = __shfl(a0, i);
            float al1 = __shfl(a1, i);
            float alpha = (lane < 32) ? al0 : al1;
            float2 v = *(const float2*)(xl + (size_t)sidx * 128 + lane * 2);
            float g0 = v.x * alpha, g1 = v.y * alpha;
            sum0 += g0; sum1 += g1;
            sq0 += g0 * g0; sq1 += g1 * g1;
            mn0 = fminf(mn0, g0); mn1 = fminf(mn1, g1);
            mx0 = fmaxf(mx0, g0); mx1 = fmaxf(mx1, g1);
        }
    } else if (deg > 64) {
        float m0 = -1e30f, m1 = -1e30f;
        for (int i = lane; i < deg; i += 64) {
            float4 c = csr4[start + i];
            m0 = fmaxf(m0, c.y); m1 = fmaxf(m1, c.z);
        }
        #pragma unroll
        for (int s = 32; s; s >>= 1) {
            m0 = fmaxf(m0, __shfl_xor(m0, s));
            m1 = fmaxf(m1, __shfl_xor(m1, s));
        }
        float s0 = 0.f, s1 = 0.f;
        for (int i = lane; i < deg; i += 64) {
            float4 c = csr4[start + i];
            s0 += __expf(c.y - m0); s1 += __expf(c.z - m1);
        }
        #pragma unroll
        for (int s = 32; s; s >>= 1) {
            s0 += __shfl_xor(s0, s);
            s1 += __shfl_xor(s1, s);
        }
        float inv0 = 1.0f / (s0 + 1e-16f), inv1 = 1.0f / (s1 + 1e-16f);
        for (int i = 0; i < deg; i++) {
            float4 c = csr4[start + i];
            int sidx = __float_as_int(c.x);
            float al0 = __expf(c.y - m0) * inv0;
            float al1 = __expf(c.z - m1) * inv1;
            float alpha = (lane < 32) ? al0 : al1;
            float2 v = *(const float2*)(xl + (size_t)sidx * 128 + lane * 2);
            float g0 = v.x * alpha, g1 = v.y * alpha;
            sum0 += g0; sum1 += g1;
            sq0 += g0 * g0; sq1 += g1 * g1;
            mn0 = fminf(mn0, g0); mn1 = fminf(mn1, g1);
            mx0 = fmaxf(mx0, g0); mx1 = fmaxf(mx1, g1);
        }
    } else {
        mn0 = mn1 = mx0 = mx1 = 0.f;
    }

    float cc = deg > 0 ? (float)deg : 1.0f;
    float mean0 = sum0 / cc, mean1 = sum1 / cc;
    float sd0 = sqrtf(fmaxf(sq0 / cc - mean0 * mean0, 0.0f) + 1e-5f);
    float sd1 = sqrtf(fmaxf(sq1 / cc - mean1 * mean1, 0.0f) + 1e-5f);

    int c2 = lane * 2, h = c2 >> 6, c = c2 & 63;
    unsigned short* ob = out_ws + (size_t)n * 512 + h * 256 + c;
    *(unsigned*)(ob + 0)   = pack2(mean0, mean1);
    *(unsigned*)(ob + 64)  = pack2(mn0, mn1);
    *(unsigned*)(ob + 128) = pack2(mx0, mx1);
    *(unsigned*)(ob + 192) = pack2(sd0, sd1);
}

// ---------------- K5: MFMA bf16 GEMM  out[64n x 128c] = A[64][512] @ W[512][128]
// LDS rows padded to 80B (bank stride 20 -> <=2-way, free).
// Epilogue per lane: node=(wave*16+lq*4+r), o=cb*16+l15; out = P1 + s1*P2 + b.
__global__ __launch_bounds__(256) void k_proj3(const unsigned short* __restrict__ Abf,
                                               const unsigned short* __restrict__ WT,
                                               const float* __restrict__ bno,
                                               const int* __restrict__ counts,
                                               const float* __restrict__ avgsum,
                                               float* __restrict__ nout) {
    __shared__ unsigned short sA[64][40];    // 64 nodes x 32k (+pad)
    __shared__ unsigned short sB[128][40];   // 128 cols x 32k (+pad)
    int t = threadIdx.x;
    int lane = t & 63, wave = t >> 6;
    int l15 = lane & 15, lq = lane >> 4;
    int n0 = blockIdx.x * 64;

    f32x4 acc[8];
    #pragma unroll
    for (int cb = 0; cb < 8; cb++) acc[cb] = (f32x4){0.f, 0.f, 0.f, 0.f};

    // staging: A -> thread t loads 16B: row t>>2, k-chunk (t&3)*8
    int arow = t >> 2, achk = (t & 3) * 8;
    int an = n0 + arow; if (an >= NN) an = NN - 1;
    const unsigned short* Aptr = Abf + (size_t)an * 512 + achk;
    // staging: B -> two 16B loads per thread
    int bcol0 = t >> 2,          bchk0 = (t & 3) * 8;
    int bcol1 = (t + 256) >> 2,  bchk1 = (t & 3) * 8;
    const unsigned short* Bptr0 = WT + (size_t)bcol0 * 512 + bchk0;
    const unsigned short* Bptr1 = WT + (size_t)bcol1 * 512 + bchk1;

    for (int kc = 0; kc < 512; kc += 32) {
        __syncthreads();
        *(uint4*)&sA[arow][achk]   = *(const uint4*)(Aptr + kc);
        *(uint4*)&sB[bcol0][bchk0] = *(const uint4*)(Bptr0 + kc);
        *(uint4*)&sB[bcol1][bchk1] = *(const uint4*)(Bptr1 + kc);
        __syncthreads();
        bf16x8 afrag = *(const bf16x8*)&sA[wave * 16 + l15][lq * 8];
        #pragma unroll
        for (int cb = 0; cb < 8; cb++) {
            bf16x8 bfrag = *(const bf16x8*)&sB[cb * 16 + l15][lq * 8];
            acc[cb] = __builtin_amdgcn_mfma_f32_16x16x32_bf16(afrag, bfrag, acc[cb], 0, 0, 0);
        }
    }

    float avg_log = *avgsum / (float)NN;
    int nodebase = n0 + wave * 16 + lq * 4;
    float s1v[4];
    #pragma unroll
    for (int r = 0; r < 4; r++) {
        int node = nodebase + r; if (node >= NN) node = NN - 1;
        float cnt = (float)counts[node];
        float ld = logf(fmaxf(cnt, 1.0f) + 1.0f);
        s1v[r] = ld / avg_log;
    }
    #pragma unroll
    for (int cb = 0; cb < 4; cb++) {
        int o = cb * 16 + l15;
        float bv = bno[o];
        #pragma unroll
        for (int r = 0; r < 4; r++) {
            int node = nodebase + r;
            if (node < NN)
                nout[(size_t)node * 64 + o] = acc[cb][r] + s1v[r] * acc[cb + 4][r] + bv;
        }
    }
}

extern "C" void kernel_launch(void* const* d_in, const int* in_sizes, int n_in,
                              void* d_out, int out_size, void* d_ws, size_t ws_size,
                              hipStream_t stream) {
    const float* x         = (const float*)d_in[0];
    const float* edge_attr = (const float*)d_in[1];
    const int*   ei        = (const int*)d_in[2];
    const float* W_l       = (const float*)d_in[3];
    const float* b_l       = (const float*)d_in[4];
    const float* W_e       = (const float*)d_in[5];
    const float* b_e       = (const float*)d_in[6];
    const float* att       = (const float*)d_in[7];
    const float* W_no      = (const float*)d_in[8];
    const float* b_no      = (const float*)d_in[9];
    const float* W_eo      = (const float*)d_in[10];
    const float* b_eo      = (const float*)d_in[11];

    float* nout = (float*)d_out;                    // [N, 64]
    float* eout = (float*)d_out + (size_t)NN * 64;  // [E, 32]

    char* ws = (char*)d_ws;
    size_t off = 0;
    auto take = [&](size_t bytes) -> char* {
        char* p = ws + off;
        off = (off + bytes + 255) & ~(size_t)255;
        return p;
    };
    float* xl        = (float*)take((size_t)NN * 128 * 4);
    float* ai        = (float*)take((size_t)NN * 2 * 4);
    float* aj        = (float*)take((size_t)NN * 2 * 4);
    float4* csr4     = (float4*)take((size_t)EE * 16);
    int*   counts    = (int*)take((size_t)NN * 4);
    int*   offsets   = (int*)take((size_t)NN * 4);
    int*   fill      = (int*)take((size_t)NN * 4);
    int*   bsums     = (int*)take(256 * 4);
    float* Wc        = (float*)take(32 * 32 * 4);
    float* bc        = (float*)take(32 * 4);
    unsigned short* WT     = (unsigned short*)take((size_t)128 * 512 * 2);
    float* avgsum    = (float*)take(4);
    unsigned short* out_ws = (unsigned short*)take((size_t)NN * 512 * 2);

    hipMemsetAsync(counts, 0, (size_t)NN * 4, stream);
    hipMemsetAsync(fill, 0, (size_t)NN * 4, stream);
    hipMemsetAsync(avgsum, 0, 4, stream);

    k_combine<<<1, 1024, 0, stream>>>(W_e, b_e, W_eo, b_eo, Wc, bc);
    k_prepw2<<<128, 512, 0, stream>>>(W_no, WT);
    k_node2<<<(NN + 63) / 64, 256, 0, stream>>>(x, W_l, b_l, att, xl, ai, aj);
    k_count<<<(EE + 255) / 256, 256, 0, stream>>>(ei, counts);
    int nb = (NN + 1023) / 1024;
    k_scan1<<<nb, 1024, 0, stream>>>(counts, offsets, bsums, avgsum);
    k_scan2<<<1, 64, 0, stream>>>(bsums, nb);
    k_scan3<<<nb, 1024, 0, stream>>>(offsets, bsums);
    k_edge4<<<EE / 256, 256, 0, stream>>>(edge_attr, ei, W_e, b_e, att, Wc, bc,
                                          ai, aj, offsets, fill, csr4, eout);
    k_aggr<<<(NN + 3) / 4, 256, 0, stream>>>(counts, offsets, csr4, xl, out_ws);
    k_proj3<<<(NN + 63) / 64, 256, 0, stream>>>(out_ws, WT, b_no, counts, avgsum, nout);
}